// Round 2
// baseline (595.868 us; speedup 1.0000x reference)
//
#include <hip/hip_runtime.h>
#include <cstdint>

// ---- problem constants ----
#define B_   64
#define T_   218
#define TP_  228          // T + 2*PAD
#define D_   512
#define M_   13952        // B_*T_  (= 109*128, exact)
#define H_   4
#define DK_  128
#define PW_  224          // padded KV width for attention (7*32)
#define N3_  1536
#define DFF_ 2048

static_assert(M_ % 128 == 0, "M tiles exact");

typedef unsigned short u16;   // raw bf16
using short8 = __attribute__((ext_vector_type(8))) short;
using f32x4  = __attribute__((ext_vector_type(4))) float;

__device__ __forceinline__ float b2f(u16 u) {
  union { float f; uint32_t i; } v; v.i = ((uint32_t)u) << 16; return v.f;
}
__device__ __forceinline__ u16 f2b(float f) {
  union { float f; uint32_t i; } v; v.f = f;
  uint32_t r = v.i + 0x7fffu + ((v.i >> 16) & 1u);
  return (u16)(r >> 16);
}
union U8 { uint4 v; u16 u[8]; };

// =====================================================================
// Generic 128x128 MFMA GEMM:  out[M,N] = A[M,K] @ Bt[N,K]^T (+ epilogue)
// A, Bt are internal bf16. bias is fp32.
// mode 0: bf16 out = acc+bias
// mode 1: f32  out = acc+bias+b2f(add_bf)+add_f   (out-proj: +fsmn+residual x)
// mode 2: bf16 out = relu(acc+bias)
// mode 3: f32  out = acc+bias+add_f               (ffn2: +residual x1)
// =====================================================================
__global__ __launch_bounds__(256, 2)
void gemm_bt(const u16* __restrict__ A, const u16* __restrict__ Bt,
             const float* __restrict__ bias, const u16* __restrict__ add_bf,
             const float* __restrict__ add_f, void* __restrict__ outp,
             int M, int N, int K, int mode)
{
  __shared__ u16 As[128][40];
  __shared__ u16 Bs[128][40];
  const int tid  = threadIdx.x;
  const int lane = tid & 63;
  const int w    = tid >> 6;
  const int wm   = (w >> 1) * 64, wn = (w & 1) * 64;
  const int l15  = lane & 15, qd = lane >> 4;
  const size_t m0 = (size_t)blockIdx.x * 128, n0 = (size_t)blockIdx.y * 128;

  const int srow = tid >> 2, scg = (tid & 3) * 8;
  const u16* Ag = A  + (m0 + srow) * (size_t)K + scg;
  const u16* Bg = Bt + (n0 + srow) * (size_t)K + scg;
  u16* Awp = &As[srow][scg];
  u16* Bwp = &Bs[srow][scg];

  const f32x4 z4 = {0.f, 0.f, 0.f, 0.f};
  f32x4 acc[4][4];
#pragma unroll
  for (int i = 0; i < 4; i++)
#pragma unroll
    for (int j = 0; j < 4; j++) acc[i][j] = z4;

  for (int k0 = 0; k0 < K; k0 += 32) {
    uint4 a0 = *(const uint4*)(Ag + k0);
    uint4 a1 = *(const uint4*)(Ag + (size_t)64 * K + k0);
    uint4 b0 = *(const uint4*)(Bg + k0);
    uint4 b1 = *(const uint4*)(Bg + (size_t)64 * K + k0);
    __syncthreads();
    *(uint4*)Awp = a0; *(uint4*)(Awp + 64 * 40) = a1;
    *(uint4*)Bwp = b0; *(uint4*)(Bwp + 64 * 40) = b1;
    __syncthreads();
    short8 af[4], bf[4];
#pragma unroll
    for (int mi = 0; mi < 4; mi++) af[mi] = *(const short8*)&As[wm + mi * 16 + l15][qd * 8];
#pragma unroll
    for (int ni = 0; ni < 4; ni++) bf[ni] = *(const short8*)&Bs[wn + ni * 16 + l15][qd * 8];
#pragma unroll
    for (int mi = 0; mi < 4; mi++)
#pragma unroll
      for (int ni = 0; ni < 4; ni++)
        acc[mi][ni] = __builtin_amdgcn_mfma_f32_16x16x32_bf16(af[mi], bf[ni], acc[mi][ni], 0, 0, 0);
  }

#pragma unroll
  for (int ni = 0; ni < 4; ni++) {
    const size_t c = n0 + wn + ni * 16 + l15;
    const float bv = bias[c];
#pragma unroll
    for (int mi = 0; mi < 4; mi++) {
      const size_t rbase = m0 + wm + mi * 16 + qd * 4;
#pragma unroll
      for (int rg = 0; rg < 4; rg++) {
        const size_t r = rbase + rg;
        float v = acc[mi][ni][rg] + bv;
        if (mode == 0) {
          ((u16*)outp)[r * (size_t)N + c] = f2b(v);
        } else if (mode == 1) {
          v += b2f(add_bf[r * (size_t)N + c]) + add_f[r * (size_t)N + c];
          ((float*)outp)[r * (size_t)N + c] = v;
        } else if (mode == 2) {
          ((u16*)outp)[r * (size_t)N + c] = f2b(fmaxf(v, 0.f));
        } else {
          v += add_f[r * (size_t)N + c];
          ((float*)outp)[r * (size_t)N + c] = v;
        }
      }
    }
  }
}

// =====================================================================
// FSMN conv1d(512,512,k=11,'same') as 11-tap accumulated GEMM.
// vmpad: (B, TP_, 512) bf16 zero-padded v*mask.  Wt: (11, 512o, 512i) bf16.
// out = (conv(vm) + vm) * mask  -> fsmnb (M,512) bf16
// grid (2 t-tiles, 4 n-tiles, B)
// =====================================================================
__global__ __launch_bounds__(256, 2)
void conv_gemm(const u16* __restrict__ vmpad, const u16* __restrict__ Wt,
               const u16* __restrict__ qkv, const float* __restrict__ masks,
               u16* __restrict__ outp)
{
  __shared__ u16 As[128][40];
  __shared__ u16 Bs[128][40];
  const int tid  = threadIdx.x;
  const int lane = tid & 63, w = tid >> 6;
  const int wm = (w >> 1) * 64, wn = (w & 1) * 64;
  const int l15 = lane & 15, qd = lane >> 4;
  const int b = blockIdx.z, t0 = blockIdx.x * 128, n0 = blockIdx.y * 128;
  const int srow = tid >> 2, scg = (tid & 3) * 8;

  const f32x4 z4 = {0.f, 0.f, 0.f, 0.f};
  f32x4 acc[4][4];
#pragma unroll
  for (int i = 0; i < 4; i++)
#pragma unroll
    for (int j = 0; j < 4; j++) acc[i][j] = z4;

  const uint4 uz = make_uint4(0, 0, 0, 0);
  for (int tap = 0; tap < 11; ++tap) {
    const int pr0 = t0 + tap + srow;
    const int pr1 = pr0 + 64;
    const bool v0 = pr0 < TP_, v1 = pr1 < TP_;
    const u16* Ab = vmpad + ((size_t)b * TP_ + t0 + tap + srow) * D_ + scg;
    const u16* Bb = Wt + ((size_t)tap * D_ + n0 + srow) * D_ + scg;
    for (int k0 = 0; k0 < D_; k0 += 32) {
      uint4 a0 = uz, a1 = uz;
      if (v0) a0 = *(const uint4*)(Ab + k0);
      if (v1) a1 = *(const uint4*)(Ab + (size_t)64 * D_ + k0);
      uint4 b0 = *(const uint4*)(Bb + k0);
      uint4 b1 = *(const uint4*)(Bb + (size_t)64 * D_ + k0);
      __syncthreads();
      *(uint4*)&As[srow][scg] = a0; *(uint4*)(&As[srow][scg] + 64 * 40) = a1;
      *(uint4*)&Bs[srow][scg] = b0; *(uint4*)(&Bs[srow][scg] + 64 * 40) = b1;
      __syncthreads();
      short8 af[4], bf[4];
#pragma unroll
      for (int mi = 0; mi < 4; mi++) af[mi] = *(const short8*)&As[wm + mi * 16 + l15][qd * 8];
#pragma unroll
      for (int ni = 0; ni < 4; ni++) bf[ni] = *(const short8*)&Bs[wn + ni * 16 + l15][qd * 8];
#pragma unroll
      for (int mi = 0; mi < 4; mi++)
#pragma unroll
        for (int ni = 0; ni < 4; ni++)
          acc[mi][ni] = __builtin_amdgcn_mfma_f32_16x16x32_bf16(af[mi], bf[ni], acc[mi][ni], 0, 0, 0);
    }
  }

#pragma unroll
  for (int ni = 0; ni < 4; ni++) {
    const int c = n0 + wn + ni * 16 + l15;
#pragma unroll
    for (int mi = 0; mi < 4; mi++) {
#pragma unroll
      for (int rg = 0; rg < 4; rg++) {
        const int t = t0 + wm + mi * 16 + qd * 4 + rg;
        if (t < T_) {
          const float m  = masks[b * T_ + t];
          const float vv = b2f(qkv[((size_t)b * T_ + t) * N3_ + 1024 + c]);
          const float val = (acc[mi][ni][rg] + vv * m) * m;
          outp[((size_t)b * T_ + t) * D_ + c] = f2b(val);
        }
      }
    }
  }
}

// =====================================================================
// Attention stage 1: P = softmax(mask(Q K^T / sqrt(dk)))  (normalized)
// grid (4 q-tiles of 64, 256 bh)
// =====================================================================
__global__ __launch_bounds__(256, 2)
void attn_scores(const u16* __restrict__ qkv, const float* __restrict__ masks,
                 u16* __restrict__ P)
{
  __shared__ u16 Qs[64][136];
  __shared__ u16 Ks[64][136];
  __shared__ float red0[4][64];
  __shared__ float red1[4][64];
  const int tid = threadIdx.x, lane = tid & 63, w = tid >> 6;
  const int l15 = lane & 15, qd = lane >> 4;
  const int bh = blockIdx.y, b = bh >> 2, h = bh & 3;
  const int q0 = blockIdx.x * 64;
  const uint4 uz = make_uint4(0, 0, 0, 0);

#pragma unroll
  for (int i = 0; i < 4; i++) {
    const int ch = tid + i * 256;
    const int row = ch >> 4, cg = (ch & 15) * 8;
    const int t = q0 + row;
    uint4 v = uz;
    if (t < T_) v = *(const uint4*)(qkv + ((size_t)b * T_ + t) * N3_ + h * DK_ + cg);
    *(uint4*)&Qs[row][cg] = v;
  }

  const f32x4 z4 = {0.f, 0.f, 0.f, 0.f};
  f32x4 acc[4][4];
#pragma unroll
  for (int i = 0; i < 4; i++)
#pragma unroll
    for (int j = 0; j < 4; j++) acc[i][j] = z4;

#pragma unroll
  for (int kc = 0; kc < 4; kc++) {
    __syncthreads();
#pragma unroll
    for (int i = 0; i < 4; i++) {
      const int ch = tid + i * 256;
      const int row = ch >> 4, cg = (ch & 15) * 8;
      const int t = kc * 64 + row;
      uint4 v = uz;
      if (t < T_) v = *(const uint4*)(qkv + ((size_t)b * T_ + t) * N3_ + D_ + h * DK_ + cg);
      *(uint4*)&Ks[row][cg] = v;
    }
    __syncthreads();
#pragma unroll
    for (int ks = 0; ks < 4; ks++) {
      short8 bf = *(const short8*)&Ks[w * 16 + l15][ks * 32 + qd * 8];
#pragma unroll
      for (int mi = 0; mi < 4; mi++) {
        short8 af = *(const short8*)&Qs[mi * 16 + l15][ks * 32 + qd * 8];
        acc[kc][mi] = __builtin_amdgcn_mfma_f32_16x16x32_bf16(af, bf, acc[kc][mi], 0, 0, 0);
      }
    }
  }

  const float scale = 0.08838834764831845f;  // 1/sqrt(128)
  const int colb = w * 16 + l15;
  bool valid[4];
#pragma unroll
  for (int kc = 0; kc < 4; kc++) {
    const int col = kc * 64 + colb;
    valid[kc] = (col < T_) && (masks[b * T_ + col] > 0.f);
  }

  float mx[4][4], sm[4][4];
#pragma unroll
  for (int mi = 0; mi < 4; mi++)
#pragma unroll
    for (int rg = 0; rg < 4; rg++) {
      float m = -1e30f;
#pragma unroll
      for (int kc = 0; kc < 4; kc++)
        if (valid[kc]) m = fmaxf(m, acc[kc][mi][rg] * scale);
      for (int d = 1; d < 16; d <<= 1) m = fmaxf(m, __shfl_xor(m, d, 64));
      mx[mi][rg] = m;
    }
  if (l15 == 0) {
#pragma unroll
    for (int mi = 0; mi < 4; mi++)
#pragma unroll
      for (int rg = 0; rg < 4; rg++) red0[w][mi * 16 + qd * 4 + rg] = mx[mi][rg];
  }
  __syncthreads();
#pragma unroll
  for (int mi = 0; mi < 4; mi++)
#pragma unroll
    for (int rg = 0; rg < 4; rg++) {
      const int r = mi * 16 + qd * 4 + rg;
      mx[mi][rg] = fmaxf(fmaxf(red0[0][r], red0[1][r]), fmaxf(red0[2][r], red0[3][r]));
    }
#pragma unroll
  for (int mi = 0; mi < 4; mi++)
#pragma unroll
    for (int rg = 0; rg < 4; rg++) {
      float s = 0.f;
#pragma unroll
      for (int kc = 0; kc < 4; kc++)
        if (valid[kc]) s += __expf(acc[kc][mi][rg] * scale - mx[mi][rg]);
      for (int d = 1; d < 16; d <<= 1) s += __shfl_xor(s, d, 64);
      sm[mi][rg] = s;
    }
  if (l15 == 0) {
#pragma unroll
    for (int mi = 0; mi < 4; mi++)
#pragma unroll
      for (int rg = 0; rg < 4; rg++) red1[w][mi * 16 + qd * 4 + rg] = sm[mi][rg];
  }
  __syncthreads();
#pragma unroll
  for (int mi = 0; mi < 4; mi++)
#pragma unroll
    for (int rg = 0; rg < 4; rg++) {
      const int r = mi * 16 + qd * 4 + rg;
      const int gq = q0 + r;
      const float inv = 1.f / (red1[0][r] + red1[1][r] + red1[2][r] + red1[3][r]);
#pragma unroll
      for (int kc = 0; kc < 4; kc++) {
        const int col = kc * 64 + colb;
        if (col < PW_) {
          const float p = valid[kc] ? __expf(acc[kc][mi][rg] * scale - mx[mi][rg]) * inv : 0.f;
          P[((size_t)bh * 256 + gq) * PW_ + col] = f2b(p);
        }
      }
    }
}

// =====================================================================
// Attention stage 2: ctx = P @ V   (A = P (256x224), Bt = Vt (128x224))
// grid (2 m-tiles, 256 bh)
// =====================================================================
__global__ __launch_bounds__(256, 2)
void attn_pv(const u16* __restrict__ P, const u16* __restrict__ Vt,
             u16* __restrict__ ctx)
{
  __shared__ u16 As[128][40];
  __shared__ u16 Bs[128][40];
  const int tid = threadIdx.x, lane = tid & 63, w = tid >> 6;
  const int wm = (w >> 1) * 64, wn = (w & 1) * 64;
  const int l15 = lane & 15, qd = lane >> 4;
  const int bh = blockIdx.y, b = bh >> 2, h = bh & 3;
  const int m0 = blockIdx.x * 128;
  const int srow = tid >> 2, scg = (tid & 3) * 8;

  const u16* Ag = P  + ((size_t)bh * 256 + m0 + srow) * PW_ + scg;
  const u16* Bg = Vt + ((size_t)bh * 128 + srow) * PW_ + scg;

  const f32x4 z4 = {0.f, 0.f, 0.f, 0.f};
  f32x4 acc[4][4];
#pragma unroll
  for (int i = 0; i < 4; i++)
#pragma unroll
    for (int j = 0; j < 4; j++) acc[i][j] = z4;

  for (int k0 = 0; k0 < PW_; k0 += 32) {
    uint4 a0 = *(const uint4*)(Ag + k0);
    uint4 a1 = *(const uint4*)(Ag + (size_t)64 * PW_ + k0);
    uint4 b0 = *(const uint4*)(Bg + k0);
    uint4 b1 = *(const uint4*)(Bg + (size_t)64 * PW_ + k0);
    __syncthreads();
    *(uint4*)&As[srow][scg] = a0; *(uint4*)(&As[srow][scg] + 64 * 40) = a1;
    *(uint4*)&Bs[srow][scg] = b0; *(uint4*)(&Bs[srow][scg] + 64 * 40) = b1;
    __syncthreads();
    short8 af[4], bf[4];
#pragma unroll
    for (int mi = 0; mi < 4; mi++) af[mi] = *(const short8*)&As[wm + mi * 16 + l15][qd * 8];
#pragma unroll
    for (int ni = 0; ni < 4; ni++) bf[ni] = *(const short8*)&Bs[wn + ni * 16 + l15][qd * 8];
#pragma unroll
    for (int mi = 0; mi < 4; mi++)
#pragma unroll
      for (int ni = 0; ni < 4; ni++)
        acc[mi][ni] = __builtin_amdgcn_mfma_f32_16x16x32_bf16(af[mi], bf[ni], acc[mi][ni], 0, 0, 0);
  }

#pragma unroll
  for (int ni = 0; ni < 4; ni++) {
    const int c = wn + ni * 16 + l15;
#pragma unroll
    for (int mi = 0; mi < 4; mi++) {
#pragma unroll
      for (int rg = 0; rg < 4; rg++) {
        const int t = m0 + wm + mi * 16 + qd * 4 + rg;
        if (t < T_)
          ctx[((size_t)b * T_ + t) * D_ + h * DK_ + c] = f2b(acc[mi][ni][rg]);
      }
    }
  }
}

// ======================= small support kernels =======================
// LayerNorm: fp32 in -> bf16 out. 4 rows/block (one per wave).
__global__ __launch_bounds__(256)
void ln_k(const float* __restrict__ x, const float* __restrict__ wgt,
          const float* __restrict__ bia, u16* __restrict__ outp)
{
  const int lane = threadIdx.x & 63, wv = threadIdx.x >> 6;
  const size_t row = (size_t)blockIdx.x * 4 + wv;
  const float* rp = x + row * D_ + lane * 8;
  float v[8], s = 0.f, s2 = 0.f;
  float4 r0 = *(const float4*)rp;
  float4 r1 = *(const float4*)(rp + 4);
  v[0] = r0.x; v[1] = r0.y; v[2] = r0.z; v[3] = r0.w;
  v[4] = r1.x; v[5] = r1.y; v[6] = r1.z; v[7] = r1.w;
#pragma unroll
  for (int i = 0; i < 8; i++) { s += v[i]; s2 += v[i] * v[i]; }
  for (int d = 1; d < 64; d <<= 1) { s += __shfl_xor(s, d, 64); s2 += __shfl_xor(s2, d, 64); }
  const float mean = s * (1.f / 512.f);
  const float var  = s2 * (1.f / 512.f) - mean * mean;
  const float rs   = rsqrtf(var + 1e-5f);
  float4 w0 = *(const float4*)(wgt + lane * 8);
  float4 w1 = *(const float4*)(wgt + lane * 8 + 4);
  float4 b0 = *(const float4*)(bia + lane * 8);
  float4 b1 = *(const float4*)(bia + lane * 8 + 4);
  const float wv8[8] = {w0.x, w0.y, w0.z, w0.w, w1.x, w1.y, w1.z, w1.w};
  const float bv8[8] = {b0.x, b0.y, b0.z, b0.w, b1.x, b1.y, b1.z, b1.w};
  U8 o;
#pragma unroll
  for (int i = 0; i < 8; i++)
    o.u[i] = f2b((v[i] - mean) * rs * wv8[i] + bv8[i]);
  *(uint4*)(outp + row * D_ + lane * 8) = o.v;
}

// dst[n*K+k] (bf16) = src[k*N+n] (fp32).  K,N multiples of 32. grid (K/32, N/32)
__global__ void transpose_kn(const float* __restrict__ src, u16* __restrict__ dst,
                             int K, int N)
{
  __shared__ float tile[32][33];
  const int k0 = blockIdx.x * 32, n0 = blockIdx.y * 32;
  const int x = threadIdx.x & 31, y = threadIdx.x >> 5;  // y in 0..7
#pragma unroll
  for (int j = 0; j < 4; j++)
    tile[y + j * 8][x] = src[(size_t)(k0 + y + j * 8) * N + n0 + x];
  __syncthreads();
#pragma unroll
  for (int j = 0; j < 4; j++)
    dst[(size_t)(n0 + y + j * 8) * K + k0 + x] = f2b(tile[x][y + j * 8]);
}

// dst[tap][o][i] (bf16) = fsmn_w[o][i][tap] (fp32). one thread per (o,i).
__global__ void reorder_fsmn(const float* __restrict__ src, u16* __restrict__ dst)
{
  const int idx = blockIdx.x * 256 + threadIdx.x;   // o*512+i, < 262144
  const float* s = src + (size_t)idx * 11;
#pragma unroll
  for (int tap = 0; tap < 11; ++tap)
    dst[(size_t)tap * 262144 + idx] = f2b(s[tap]);
}

// vmpad(B,TP_,512) bf16 = zero-padded v*mask   grid (57, B)
__global__ void fill_vmpad(const u16* __restrict__ qkv, const float* __restrict__ masks,
                           u16* __restrict__ vmpad)
{
  const int b  = blockIdx.y;
  const int i8 = blockIdx.x * 256 + threadIdx.x;   // < 14592
  const int e  = i8 * 8;
  const int c  = e & 511, p = e >> 9;
  const int t  = p - 5;
  uint4 v = make_uint4(0, 0, 0, 0);
  if (t >= 0 && t < T_) {
    U8 raw; raw.v = *(const uint4*)(qkv + ((size_t)b * T_ + t) * N3_ + 1024 + c);
    const float m = masks[b * T_ + t];
    U8 o;
#pragma unroll
    for (int i = 0; i < 8; i++) o.u[i] = f2b(b2f(raw.u[i]) * m);
    v = o.v;
  }
  *(uint4*)(vmpad + (size_t)b * TP_ * D_ + e) = v;
}

// Vt[bh][d][kv] = v[b, kv, h*128+d]  grid (7 kv-tiles, 4 d-tiles, 256 bh)
__global__ void fill_vt(const u16* __restrict__ qkv, u16* __restrict__ Vt)
{
  __shared__ u16 tile[32][33];
  const int bh = blockIdx.z, b = bh >> 2, h = bh & 3;
  const int kv0 = blockIdx.x * 32, d0 = blockIdx.y * 32;
  const int x = threadIdx.x & 31, y = threadIdx.x >> 5;
#pragma unroll
  for (int j = 0; j < 4; j++) {
    const int kv = kv0 + y + j * 8;
    u16 v = 0;
    if (kv < T_) v = qkv[((size_t)b * T_ + kv) * N3_ + 1024 + h * DK_ + d0 + x];
    tile[y + j * 8][x] = v;
  }
  __syncthreads();
#pragma unroll
  for (int j = 0; j < 4; j++) {
    const int d = d0 + y + j * 8;
    Vt[((size_t)bh * 128 + d) * PW_ + kv0 + x] = tile[x][y + j * 8];
  }
}

// =====================================================================
extern "C" void kernel_launch(void* const* d_in, const int* in_sizes, int n_in,
                              void* d_out, int out_size, void* d_ws, size_t ws_size,
                              hipStream_t stream)
{
  const float* x      = (const float*)d_in[0];
  const float* masks  = (const float*)d_in[1];
  const float* ln0_w  = (const float*)d_in[2];
  const float* ln0_b  = (const float*)d_in[3];
  const float* ln1_w  = (const float*)d_in[4];
  const float* ln1_b  = (const float*)d_in[5];
  const float* qkv_w  = (const float*)d_in[6];
  const float* qkv_b  = (const float*)d_in[7];
  const float* out_w  = (const float*)d_in[8];
  const float* out_b  = (const float*)d_in[9];
  const float* fsmn_w = (const float*)d_in[10];
  const float* w1     = (const float*)d_in[11];
  const float* b1     = (const float*)d_in[12];
  const float* w2     = (const float*)d_in[13];
  const float* b2     = (const float*)d_in[14];
  float* outp = (float*)d_out;
  u16* ws   = (u16*)d_ws;

  size_t off = 0;
  u16* qkv_wT = ws + off; off += (size_t)1536 * 512;
  u16* out_wT = ws + off; off += (size_t)512 * 512;
  u16* w1T    = ws + off; off += (size_t)2048 * 512;
  u16* w2T    = ws + off; off += (size_t)512 * 2048;
  u16* fsmnT  = ws + off; off += (size_t)11 * 512 * 512;
  u16* slotA  = ws + off; off += (size_t)M_ * 512;        // h (ln0) -> ctx
  u16* qkvb   = ws + off; off += (size_t)M_ * 1536;       // qkv -> h1
  u16* vmpad  = ws + off; off += (size_t)B_ * TP_ * 512;  // vmpad
  u16* fsmnb  = ws + off; off += (size_t)M_ * 512;
  u16* regionX= ws + off; off += (size_t)M_ * 2048;       // P+Vt -> hid
  float* x1   = (float*)(ws + off); off += (size_t)2 * M_ * 512;  // fp32 residual stream
  u16* Pbuf  = regionX;
  u16* Vtbuf = regionX + (size_t)256 * 256 * PW_;
  u16* hid   = regionX;
  u16* h1    = qkvb;

  // weight prep (fp32 -> bf16, transposed to N x K)
  transpose_kn<<<dim3(512 / 32, 1536 / 32), 256, 0, stream>>>(qkv_w, qkv_wT, 512, 1536);
  transpose_kn<<<dim3(512 / 32, 512 / 32), 256, 0, stream>>>(out_w, out_wT, 512, 512);
  transpose_kn<<<dim3(512 / 32, 2048 / 32), 256, 0, stream>>>(w1, w1T, 512, 2048);
  transpose_kn<<<dim3(2048 / 32, 512 / 32), 256, 0, stream>>>(w2, w2T, 2048, 512);
  reorder_fsmn<<<262144 / 256, 256, 0, stream>>>(fsmn_w, fsmnT);

  // ln0 -> h
  ln_k<<<M_ / 4, 256, 0, stream>>>(x, ln0_w, ln0_b, slotA);
  // qkv = h @ qkv_w + b   (bf16 out)
  gemm_bt<<<dim3(M_ / 128, 1536 / 128), 256, 0, stream>>>(
      slotA, qkv_wT, qkv_b, nullptr, nullptr, qkvb, M_, 1536, 512, 0);
  // fsmn branch
  fill_vmpad<<<dim3(57, B_), 256, 0, stream>>>(qkvb, masks, vmpad);
  conv_gemm<<<dim3(2, 4, B_), 256, 0, stream>>>(vmpad, fsmnT, qkvb, masks, fsmnb);
  // attention
  fill_vt<<<dim3(7, 4, 256), 256, 0, stream>>>(qkvb, Vtbuf);
  attn_scores<<<dim3(4, 256), 256, 0, stream>>>(qkvb, masks, Pbuf);
  attn_pv<<<dim3(2, 256), 256, 0, stream>>>(Pbuf, Vtbuf, slotA);
  // x1 = x + ctx@out_w + out_b + fsmn   (fp32 out)
  gemm_bt<<<dim3(M_ / 128, 512 / 128), 256, 0, stream>>>(
      slotA, out_wT, out_b, fsmnb, x, x1, M_, 512, 512, 1);
  // ffn
  ln_k<<<M_ / 4, 256, 0, stream>>>(x1, ln1_w, ln1_b, h1);
  gemm_bt<<<dim3(M_ / 128, 2048 / 128), 256, 0, stream>>>(
      h1, w1T, b1, nullptr, nullptr, hid, M_, 2048, 512, 2);
  gemm_bt<<<dim3(M_ / 128, 512 / 128), 256, 0, stream>>>(
      hid, w2T, b2, nullptr, x1, outp, M_, 512, 2048, 3);
}

// Round 3
// 549.478 us; speedup vs baseline: 1.0844x; 1.0844x over previous
//
#include <hip/hip_runtime.h>
#include <cstdint>

// ---- problem constants ----
#define B_   64
#define T_   218
#define TP_  228          // T + 2*PAD
#define D_   512
#define M_   13952        // B_*T_  (= 109*128, exact)
#define H_   4
#define DK_  128
#define PW_  224          // padded KV width for attention (7*32)
#define N3_  1536
#define DFF_ 2048
#define KC_  5632         // conv im2col K = 11*512

static_assert(M_ % 128 == 0, "M tiles exact");

typedef unsigned short u16;   // raw bf16
using short8 = __attribute__((ext_vector_type(8))) short;
using f32x4  = __attribute__((ext_vector_type(4))) float;

__device__ __forceinline__ float b2f(u16 u) {
  union { float f; uint32_t i; } v; v.i = ((uint32_t)u) << 16; return v.f;
}
__device__ __forceinline__ u16 f2b(float f) {
  union { float f; uint32_t i; } v; v.f = f;
  uint32_t r = v.i + 0x7fffu + ((v.i >> 16) & 1u);
  return (u16)(r >> 16);
}
union U8 { uint4 v; u16 u[8]; };

// async global->LDS, 16 bytes per lane; LDS dest is wave-uniform base + lane*16
__device__ __forceinline__ void gll16(const u16* g, u16* l) {
  __builtin_amdgcn_global_load_lds(
      (const __attribute__((address_space(1))) unsigned int*)g,
      (__attribute__((address_space(3))) unsigned int*)l, 16, 0, 0);
}

// =====================================================================
// Unified 128x128 MFMA GEMM with global_load_lds staging (m97 structure).
// out[M,N] = A[M,K] (row stride sA) @ Bt[N,K]^T, + per-mode epilogue.
// MODE 0: bf16 out = acc+bias                         (qkv)
// MODE 1: f32  out = acc+bias+b2f(add_bf)+add_f       (out-proj +fsmn +x)
// MODE 2: bf16 out = relu(acc+bias)                   (ffn1)
// MODE 3: f32  out = acc+bias+add_f                   (ffn2 +x1 -> d_out)
// MODE 4: conv im2col: z=batch, bf16 out=(acc+vm)*m   (fsmn)
// MODE 5: attn PV: z=bh, bf16 ctx out                 (P@V)
// =====================================================================
template<int MODE>
__global__ __launch_bounds__(256, 2)
void gemm_u(const u16* __restrict__ A, int sA, const u16* __restrict__ Bt,
            const float* __restrict__ bias, const u16* __restrict__ add_bf,
            const float* __restrict__ add_f, void* __restrict__ outp,
            int N, int K, const float* __restrict__ masks)
{
  __shared__ u16 As[128 * 32];
  __shared__ u16 Bs[128 * 32];
  const int tid = threadIdx.x, lane = tid & 63, w = tid >> 6;
  const int wm = (w >> 1) * 64, wn = (w & 1) * 64;
  const int l15 = lane & 15, qd = lane >> 4;
  const int zb = blockIdx.z;
  const int m0 = blockIdx.x * 128, n0 = blockIdx.y * 128;

  const u16* Ab  = A;
  const u16* Btb = Bt;
  if (MODE == 4) Ab = A + (size_t)zb * TP_ * D_;
  if (MODE == 5) { Ab = A + (size_t)zb * 256 * PW_; Btb = Bt + (size_t)zb * 128 * PW_; }

  // staging addresses: wave w, issue j in {0,1}; lane covers (row = j*64 + w*16
  // + lane/4, 16B chunk = lane%4) of the 128x32 tile.
  const int rl = lane >> 2, ce = (lane & 3) * 8;
  int ra0 = m0 + w * 16 + rl, ra1 = ra0 + 64;
  if (MODE == 4) { ra0 = min(ra0, T_ - 1); ra1 = min(ra1, T_ - 1); }  // clamp: masked later
  const u16* ag0 = Ab + (size_t)ra0 * sA + ce;
  const u16* ag1 = Ab + (size_t)ra1 * sA + ce;
  const u16* bg0 = Btb + (size_t)(n0 + w * 16 + rl) * K + ce;
  const u16* bg1 = bg0 + (size_t)64 * K;
  u16* lA0 = As + w * 512;
  u16* lA1 = As + 2048 + w * 512;
  u16* lB0 = Bs + w * 512;
  u16* lB1 = Bs + 2048 + w * 512;

  const f32x4 z4 = {0.f, 0.f, 0.f, 0.f};
  f32x4 acc[4][4];
#pragma unroll
  for (int i = 0; i < 4; i++)
#pragma unroll
    for (int j = 0; j < 4; j++) acc[i][j] = z4;

  for (int k0 = 0; k0 < K; k0 += 32) {
    __syncthreads();
    gll16(ag0 + k0, lA0);
    gll16(ag1 + k0, lA1);
    gll16(bg0 + k0, lB0);
    gll16(bg1 + k0, lB1);
    __syncthreads();
    short8 af[4], bf[4];
#pragma unroll
    for (int mi = 0; mi < 4; mi++) af[mi] = *(const short8*)&As[(wm + mi * 16 + l15) * 32 + qd * 8];
#pragma unroll
    for (int ni = 0; ni < 4; ni++) bf[ni] = *(const short8*)&Bs[(wn + ni * 16 + l15) * 32 + qd * 8];
#pragma unroll
    for (int mi = 0; mi < 4; mi++)
#pragma unroll
      for (int ni = 0; ni < 4; ni++)
        acc[mi][ni] = __builtin_amdgcn_mfma_f32_16x16x32_bf16(af[mi], bf[ni], acc[mi][ni], 0, 0, 0);
  }

#pragma unroll
  for (int ni = 0; ni < 4; ni++) {
    const int c = n0 + wn + ni * 16 + l15;
    const float bv = (MODE == 4 || MODE == 5) ? 0.f : bias[c];
#pragma unroll
    for (int mi = 0; mi < 4; mi++) {
#pragma unroll
      for (int rg = 0; rg < 4; rg++) {
        const int r = m0 + wm + mi * 16 + qd * 4 + rg;
        float v = acc[mi][ni][rg] + bv;
        if (MODE == 0) {
          ((u16*)outp)[(size_t)r * N + c] = f2b(v);
        } else if (MODE == 1) {
          const size_t idx = (size_t)r * N + c;
          ((float*)outp)[idx] = v + b2f(add_bf[idx]) + add_f[idx];
        } else if (MODE == 2) {
          ((u16*)outp)[(size_t)r * N + c] = f2b(fmaxf(v, 0.f));
        } else if (MODE == 3) {
          const size_t idx = (size_t)r * N + c;
          ((float*)outp)[idx] = v + add_f[idx];
        } else if (MODE == 4) {
          const int t = r;
          if (t < T_) {
            const float m  = masks[zb * T_ + t];
            const float vm = b2f(Ab[(size_t)(t + 5) * D_ + c]);  // v*mask (center tap row)
            ((u16*)outp)[((size_t)zb * T_ + t) * D_ + c] = f2b((v + vm) * m);
          }
        } else {  // MODE 5
          const int t = r;
          if (t < T_) {
            const int b = zb >> 2, h = zb & 3;
            ((u16*)outp)[((size_t)b * T_ + t) * D_ + h * DK_ + c] = f2b(v);
          }
        }
      }
    }
  }
}

// =====================================================================
// Attention stage 1: P = softmax(mask(Q K^T / sqrt(dk)))  (normalized)
// grid (4 q-tiles of 64, 256 bh)
// =====================================================================
__global__ __launch_bounds__(256, 2)
void attn_scores(const u16* __restrict__ qkv, const float* __restrict__ masks,
                 u16* __restrict__ P)
{
  __shared__ u16 Qs[64][136];
  __shared__ u16 Ks[64][136];
  __shared__ float red0[4][64];
  __shared__ float red1[4][64];
  const int tid = threadIdx.x, lane = tid & 63, w = tid >> 6;
  const int l15 = lane & 15, qd = lane >> 4;
  const int bh = blockIdx.y, b = bh >> 2, h = bh & 3;
  const int q0 = blockIdx.x * 64;
  const uint4 uz = make_uint4(0, 0, 0, 0);

#pragma unroll
  for (int i = 0; i < 4; i++) {
    const int ch = tid + i * 256;
    const int row = ch >> 4, cg = (ch & 15) * 8;
    const int t = q0 + row;
    uint4 v = uz;
    if (t < T_) v = *(const uint4*)(qkv + ((size_t)b * T_ + t) * N3_ + h * DK_ + cg);
    *(uint4*)&Qs[row][cg] = v;
  }

  const f32x4 z4 = {0.f, 0.f, 0.f, 0.f};
  f32x4 acc[4][4];
#pragma unroll
  for (int i = 0; i < 4; i++)
#pragma unroll
    for (int j = 0; j < 4; j++) acc[i][j] = z4;

#pragma unroll
  for (int kc = 0; kc < 4; kc++) {
    __syncthreads();
#pragma unroll
    for (int i = 0; i < 4; i++) {
      const int ch = tid + i * 256;
      const int row = ch >> 4, cg = (ch & 15) * 8;
      const int t = kc * 64 + row;
      uint4 v = uz;
      if (t < T_) v = *(const uint4*)(qkv + ((size_t)b * T_ + t) * N3_ + D_ + h * DK_ + cg);
      *(uint4*)&Ks[row][cg] = v;
    }
    __syncthreads();
#pragma unroll
    for (int ks = 0; ks < 4; ks++) {
      short8 bf = *(const short8*)&Ks[w * 16 + l15][ks * 32 + qd * 8];
#pragma unroll
      for (int mi = 0; mi < 4; mi++) {
        short8 af = *(const short8*)&Qs[mi * 16 + l15][ks * 32 + qd * 8];
        acc[kc][mi] = __builtin_amdgcn_mfma_f32_16x16x32_bf16(af, bf, acc[kc][mi], 0, 0, 0);
      }
    }
  }

  const float scale = 0.08838834764831845f;  // 1/sqrt(128)
  const int colb = w * 16 + l15;
  bool valid[4];
#pragma unroll
  for (int kc = 0; kc < 4; kc++) {
    const int col = kc * 64 + colb;
    valid[kc] = (col < T_) && (masks[b * T_ + col] > 0.f);
  }

  float mx[4][4], sm[4][4];
#pragma unroll
  for (int mi = 0; mi < 4; mi++)
#pragma unroll
    for (int rg = 0; rg < 4; rg++) {
      float m = -1e30f;
#pragma unroll
      for (int kc = 0; kc < 4; kc++)
        if (valid[kc]) m = fmaxf(m, acc[kc][mi][rg] * scale);
      for (int d = 1; d < 16; d <<= 1) m = fmaxf(m, __shfl_xor(m, d, 64));
      mx[mi][rg] = m;
    }
  if (l15 == 0) {
#pragma unroll
    for (int mi = 0; mi < 4; mi++)
#pragma unroll
      for (int rg = 0; rg < 4; rg++) red0[w][mi * 16 + qd * 4 + rg] = mx[mi][rg];
  }
  __syncthreads();
#pragma unroll
  for (int mi = 0; mi < 4; mi++)
#pragma unroll
    for (int rg = 0; rg < 4; rg++) {
      const int r = mi * 16 + qd * 4 + rg;
      mx[mi][rg] = fmaxf(fmaxf(red0[0][r], red0[1][r]), fmaxf(red0[2][r], red0[3][r]));
    }
#pragma unroll
  for (int mi = 0; mi < 4; mi++)
#pragma unroll
    for (int rg = 0; rg < 4; rg++) {
      float s = 0.f;
#pragma unroll
      for (int kc = 0; kc < 4; kc++)
        if (valid[kc]) s += __expf(acc[kc][mi][rg] * scale - mx[mi][rg]);
      for (int d = 1; d < 16; d <<= 1) s += __shfl_xor(s, d, 64);
      sm[mi][rg] = s;
    }
  if (l15 == 0) {
#pragma unroll
    for (int mi = 0; mi < 4; mi++)
#pragma unroll
      for (int rg = 0; rg < 4; rg++) red1[w][mi * 16 + qd * 4 + rg] = sm[mi][rg];
  }
  __syncthreads();
#pragma unroll
  for (int mi = 0; mi < 4; mi++)
#pragma unroll
    for (int rg = 0; rg < 4; rg++) {
      const int r = mi * 16 + qd * 4 + rg;
      const int gq = q0 + r;
      const float inv = 1.f / (red1[0][r] + red1[1][r] + red1[2][r] + red1[3][r]);
#pragma unroll
      for (int kc = 0; kc < 4; kc++) {
        const int col = kc * 64 + colb;
        if (col < PW_) {
          const float p = valid[kc] ? __expf(acc[kc][mi][rg] * scale - mx[mi][rg]) * inv : 0.f;
          P[((size_t)bh * 256 + gq) * PW_ + col] = f2b(p);
        }
      }
    }
}

// ======================= small support kernels =======================
// LayerNorm: fp32 in -> bf16 out. 4 rows/block (one per wave).
__global__ __launch_bounds__(256)
void ln_k(const float* __restrict__ x, const float* __restrict__ wgt,
          const float* __restrict__ bia, u16* __restrict__ outp)
{
  const int lane = threadIdx.x & 63, wv = threadIdx.x >> 6;
  const size_t row = (size_t)blockIdx.x * 4 + wv;
  const float* rp = x + row * D_ + lane * 8;
  float v[8], s = 0.f, s2 = 0.f;
  float4 r0 = *(const float4*)rp;
  float4 r1 = *(const float4*)(rp + 4);
  v[0] = r0.x; v[1] = r0.y; v[2] = r0.z; v[3] = r0.w;
  v[4] = r1.x; v[5] = r1.y; v[6] = r1.z; v[7] = r1.w;
#pragma unroll
  for (int i = 0; i < 8; i++) { s += v[i]; s2 += v[i] * v[i]; }
  for (int d = 1; d < 64; d <<= 1) { s += __shfl_xor(s, d, 64); s2 += __shfl_xor(s2, d, 64); }
  const float mean = s * (1.f / 512.f);
  const float var  = s2 * (1.f / 512.f) - mean * mean;
  const float rs   = rsqrtf(var + 1e-5f);
  float4 w0 = *(const float4*)(wgt + lane * 8);
  float4 w1 = *(const float4*)(wgt + lane * 8 + 4);
  float4 b0 = *(const float4*)(bia + lane * 8);
  float4 b1 = *(const float4*)(bia + lane * 8 + 4);
  const float wv8[8] = {w0.x, w0.y, w0.z, w0.w, w1.x, w1.y, w1.z, w1.w};
  const float bv8[8] = {b0.x, b0.y, b0.z, b0.w, b1.x, b1.y, b1.z, b1.w};
  U8 o;
#pragma unroll
  for (int i = 0; i < 8; i++)
    o.u[i] = f2b((v[i] - mean) * rs * wv8[i] + bv8[i]);
  *(uint4*)(outp + row * D_ + lane * 8) = o.v;
}

// dst[n*K+k] (bf16) = src[k*N+n] (fp32).  K,N multiples of 32. grid (K/32, N/32)
__global__ void transpose_kn(const float* __restrict__ src, u16* __restrict__ dst,
                             int K, int N)
{
  __shared__ float tile[32][33];
  const int k0 = blockIdx.x * 32, n0 = blockIdx.y * 32;
  const int x = threadIdx.x & 31, y = threadIdx.x >> 5;  // y in 0..7
#pragma unroll
  for (int j = 0; j < 4; j++)
    tile[y + j * 8][x] = src[(size_t)(k0 + y + j * 8) * N + n0 + x];
  __syncthreads();
#pragma unroll
  for (int j = 0; j < 4; j++)
    dst[(size_t)(n0 + y + j * 8) * K + k0 + x] = f2b(tile[x][y + j * 8]);
}

// W2[o][tap*512+i] (bf16) = fsmn_w[o][i][tap] (fp32). one thread per (o,i).
__global__ void reorder_fsmn(const float* __restrict__ src, u16* __restrict__ dst)
{
  const int idx = blockIdx.x * 256 + threadIdx.x;   // o*512+i, < 262144
  const int o = idx >> 9, i = idx & 511;
  const float* s = src + (size_t)idx * 11;
#pragma unroll
  for (int tap = 0; tap < 11; ++tap)
    dst[(size_t)o * KC_ + tap * 512 + i] = f2b(s[tap]);
}

// vmpad(B,TP_,512) bf16 = zero-padded v*mask   grid (57, B)
__global__ void fill_vmpad(const u16* __restrict__ qkv, const float* __restrict__ masks,
                           u16* __restrict__ vmpad)
{
  const int b  = blockIdx.y;
  const int i8 = blockIdx.x * 256 + threadIdx.x;   // < 14592
  const int e  = i8 * 8;
  const int c  = e & 511, p = e >> 9;
  const int t  = p - 5;
  uint4 v = make_uint4(0, 0, 0, 0);
  if (t >= 0 && t < T_) {
    U8 raw; raw.v = *(const uint4*)(qkv + ((size_t)b * T_ + t) * N3_ + 1024 + c);
    const float m = masks[b * T_ + t];
    U8 o;
#pragma unroll
    for (int i = 0; i < 8; i++) o.u[i] = f2b(b2f(raw.u[i]) * m);
    v = o.v;
  }
  *(uint4*)(vmpad + (size_t)b * TP_ * D_ + e) = v;
}

// Vt[bh][d][kv] = v[b, kv, h*128+d]  grid (7 kv-tiles, 4 d-tiles, 256 bh)
__global__ void fill_vt(const u16* __restrict__ qkv, u16* __restrict__ Vt)
{
  __shared__ u16 tile[32][33];
  const int bh = blockIdx.z, b = bh >> 2, h = bh & 3;
  const int kv0 = blockIdx.x * 32, d0 = blockIdx.y * 32;
  const int x = threadIdx.x & 31, y = threadIdx.x >> 5;
#pragma unroll
  for (int j = 0; j < 4; j++) {
    const int kv = kv0 + y + j * 8;
    u16 v = 0;
    if (kv < T_) v = qkv[((size_t)b * T_ + kv) * N3_ + 1024 + h * DK_ + d0 + x];
    tile[y + j * 8][x] = v;
  }
  __syncthreads();
#pragma unroll
  for (int j = 0; j < 4; j++) {
    const int d = d0 + y + j * 8;
    Vt[((size_t)bh * 128 + d) * PW_ + kv0 + x] = tile[x][y + j * 8];
  }
}

// =====================================================================
extern "C" void kernel_launch(void* const* d_in, const int* in_sizes, int n_in,
                              void* d_out, int out_size, void* d_ws, size_t ws_size,
                              hipStream_t stream)
{
  const float* x      = (const float*)d_in[0];
  const float* masks  = (const float*)d_in[1];
  const float* ln0_w  = (const float*)d_in[2];
  const float* ln0_b  = (const float*)d_in[3];
  const float* ln1_w  = (const float*)d_in[4];
  const float* ln1_b  = (const float*)d_in[5];
  const float* qkv_w  = (const float*)d_in[6];
  const float* qkv_b  = (const float*)d_in[7];
  const float* out_w  = (const float*)d_in[8];
  const float* out_b  = (const float*)d_in[9];
  const float* fsmn_w = (const float*)d_in[10];
  const float* w1     = (const float*)d_in[11];
  const float* b1     = (const float*)d_in[12];
  const float* w2     = (const float*)d_in[13];
  const float* b2     = (const float*)d_in[14];
  float* outp = (float*)d_out;
  u16* ws   = (u16*)d_ws;

  size_t off = 0;
  u16* qkv_wT = ws + off; off += (size_t)1536 * 512;
  u16* out_wT = ws + off; off += (size_t)512 * 512;
  u16* w1T    = ws + off; off += (size_t)2048 * 512;
  u16* w2T    = ws + off; off += (size_t)512 * 2048;
  u16* fsmnW2 = ws + off; off += (size_t)512 * KC_;       // (512o, 5632k)
  u16* slotA  = ws + off; off += (size_t)M_ * 512;        // h (ln0) -> ctx
  u16* qkvb   = ws + off; off += (size_t)M_ * 1536;       // qkv -> h1
  u16* vmpad  = ws + off; off += (size_t)B_ * TP_ * 512;  // vmpad
  u16* fsmnb  = ws + off; off += (size_t)M_ * 512;
  u16* regionX= ws + off; off += (size_t)M_ * 2048;       // P+Vt -> hid
  float* x1   = (float*)(ws + off); off += (size_t)2 * M_ * 512;  // fp32 residual
  u16* Pbuf  = regionX;
  u16* Vtbuf = regionX + (size_t)256 * 256 * PW_;
  u16* hid   = regionX;
  u16* h1    = qkvb;

  // weight prep (fp32 -> bf16, transposed to N x K)
  transpose_kn<<<dim3(512 / 32, 1536 / 32), 256, 0, stream>>>(qkv_w, qkv_wT, 512, 1536);
  transpose_kn<<<dim3(512 / 32, 512 / 32), 256, 0, stream>>>(out_w, out_wT, 512, 512);
  transpose_kn<<<dim3(512 / 32, 2048 / 32), 256, 0, stream>>>(w1, w1T, 512, 2048);
  transpose_kn<<<dim3(2048 / 32, 512 / 32), 256, 0, stream>>>(w2, w2T, 2048, 512);
  reorder_fsmn<<<262144 / 256, 256, 0, stream>>>(fsmn_w, fsmnW2);

  // ln0 -> h
  ln_k<<<M_ / 4, 256, 0, stream>>>(x, ln0_w, ln0_b, slotA);
  // qkv = h @ qkv_w + b   (bf16 out)
  gemm_u<0><<<dim3(M_ / 128, 1536 / 128, 1), 256, 0, stream>>>(
      slotA, 512, qkv_wT, qkv_b, nullptr, nullptr, qkvb, 1536, 512, nullptr);
  // fsmn branch: conv as strided im2col GEMM, K=5632
  fill_vmpad<<<dim3(57, B_), 256, 0, stream>>>(qkvb, masks, vmpad);
  gemm_u<4><<<dim3(2, 4, B_), 256, 0, stream>>>(
      vmpad, 512, fsmnW2, nullptr, nullptr, nullptr, fsmnb, 512, KC_, masks);
  // attention
  fill_vt<<<dim3(7, 4, 256), 256, 0, stream>>>(qkvb, Vtbuf);
  attn_scores<<<dim3(4, 256), 256, 0, stream>>>(qkvb, masks, Pbuf);
  gemm_u<5><<<dim3(2, 1, 256), 256, 0, stream>>>(
      Pbuf, PW_, Vtbuf, nullptr, nullptr, nullptr, slotA, 128, PW_, nullptr);
  // x1 = x + ctx@out_w + out_b + fsmn   (fp32 out)
  gemm_u<1><<<dim3(M_ / 128, 512 / 128, 1), 256, 0, stream>>>(
      slotA, 512, out_wT, out_b, fsmnb, x, x1, 512, 512, nullptr);
  // ffn
  ln_k<<<M_ / 4, 256, 0, stream>>>(x1, ln1_w, ln1_b, h1);
  gemm_u<2><<<dim3(M_ / 128, 2048 / 128, 1), 256, 0, stream>>>(
      h1, 512, w1T, b1, nullptr, nullptr, hid, 2048, 512, nullptr);
  gemm_u<3><<<dim3(M_ / 128, 512 / 128, 1), 256, 0, stream>>>(
      hid, 2048, w2T, b2, nullptr, x1, outp, 512, 2048, nullptr);
}

// Round 4
// 548.076 us; speedup vs baseline: 1.0872x; 1.0026x over previous
//
#include <hip/hip_runtime.h>
#include <cstdint>

// ---- problem constants ----
#define B_   64
#define T_   218
#define TP_  228          // T + 2*PAD
#define D_   512
#define M_   13952        // B_*T_  (= 109*128, exact)
#define H_   4
#define DK_  128
#define PW_  224          // padded KV width for attention (7*32)
#define N3_  1536
#define DFF_ 2048
#define KC_  5632         // conv im2col K = 11*512
#define KH_  2816         // conv split-K half

static_assert(M_ % 128 == 0, "M tiles exact");

typedef unsigned short u16;   // raw bf16
using short8 = __attribute__((ext_vector_type(8))) short;
using f32x4  = __attribute__((ext_vector_type(4))) float;

__device__ __forceinline__ float b2f(u16 u) {
  union { float f; uint32_t i; } v; v.i = ((uint32_t)u) << 16; return v.f;
}
__device__ __forceinline__ u16 f2b(float f) {
  union { float f; uint32_t i; } v; v.f = f;
  uint32_t r = v.i + 0x7fffu + ((v.i >> 16) & 1u);
  return (u16)(r >> 16);
}
union U8 { uint4 v; u16 u[8]; };

// async global->LDS, 16 bytes per lane; LDS dest is wave-uniform base + lane*16
__device__ __forceinline__ void gll16(const u16* g, u16* l) {
  __builtin_amdgcn_global_load_lds(
      (const __attribute__((address_space(1))) unsigned int*)g,
      (__attribute__((address_space(3))) unsigned int*)l, 16, 0, 0);
}

// =====================================================================
// Unified 128x128 MFMA GEMM with global_load_lds staging (m97 structure).
// out[M,N] = A[M,K] (row stride sA) @ Bt[N,K]^T (row stride sB), + epilogue.
// MODE 0: bf16 out = acc+bias; v-cols also write vmpad (qkv)
// MODE 1: f32  out = acc+bias+(accin+vm)*m+add_f      (out-proj +fsmn +x)
// MODE 2: bf16 out = relu(acc+bias)                   (ffn1)
// MODE 3: f32  out = acc+bias+add_f                   (ffn2 +x1 -> d_out)
// MODE 4: conv im2col split-K: z=K-half, atomicAdd f32 (fsmn partial)
// MODE 5: attn PV: z=bh, bf16 ctx out                 (P@V)
// =====================================================================
template<int MODE>
__global__ __launch_bounds__(256, 2)
void gemm_u(const u16* __restrict__ A, int sA, const u16* __restrict__ Bt, int sB,
            const float* __restrict__ bias, const float* __restrict__ accin,
            const u16* __restrict__ vmp, u16* __restrict__ vmout,
            const float* __restrict__ add_f, void* __restrict__ outp,
            int N, int K, const float* __restrict__ masks)
{
  __shared__ u16 As[128 * 32];
  __shared__ u16 Bs[128 * 32];
  const int tid = threadIdx.x, lane = tid & 63, w = tid >> 6;
  const int wm = (w >> 1) * 64, wn = (w & 1) * 64;
  const int l15 = lane & 15, qd = lane >> 4;
  const int zb = blockIdx.z;
  const int m0 = blockIdx.x * 128, n0 = blockIdx.y * 128;

  const u16* Ab  = A;
  const u16* Btb = Bt;
  if (MODE == 5) { Ab = A + (size_t)zb * 256 * PW_; Btb = Bt + (size_t)zb * 128 * PW_; }

  // staging: wave w, issue j in {0,1}; lane covers row = j*64 + w*16 + lane/4,
  // 16B chunk = lane%4 of the 128x32 tile.
  const int rl = lane >> 2, ce = (lane & 3) * 8;
  const int r0 = m0 + w * 16 + rl, r1 = r0 + 64;
  size_t aoff0, aoff1, bkoff = 0;
  if (MODE == 4) {
    const int b0r = r0 / T_, t0r = r0 - b0r * T_;
    const int b1r = r1 / T_, t1r = r1 - b1r * T_;
    aoff0 = ((size_t)b0r * TP_ + t0r) * D_ + (size_t)zb * KH_;
    aoff1 = ((size_t)b1r * TP_ + t1r) * D_ + (size_t)zb * KH_;
    bkoff = (size_t)zb * KH_;
  } else {
    aoff0 = (size_t)r0 * sA;
    aoff1 = (size_t)r1 * sA;
  }
  const u16* ag0 = Ab + aoff0 + ce;
  const u16* ag1 = Ab + aoff1 + ce;
  const u16* bg0 = Btb + (size_t)(n0 + w * 16 + rl) * sB + bkoff + ce;
  const u16* bg1 = bg0 + (size_t)64 * sB;
  u16* lA0 = As + w * 512;
  u16* lA1 = As + 2048 + w * 512;
  u16* lB0 = Bs + w * 512;
  u16* lB1 = Bs + 2048 + w * 512;

  const f32x4 z4 = {0.f, 0.f, 0.f, 0.f};
  f32x4 acc[4][4];
#pragma unroll
  for (int i = 0; i < 4; i++)
#pragma unroll
    for (int j = 0; j < 4; j++) acc[i][j] = z4;

  for (int k0 = 0; k0 < K; k0 += 32) {
    __syncthreads();
    gll16(ag0 + k0, lA0);
    gll16(ag1 + k0, lA1);
    gll16(bg0 + k0, lB0);
    gll16(bg1 + k0, lB1);
    __syncthreads();
    short8 af[4], bf[4];
#pragma unroll
    for (int mi = 0; mi < 4; mi++) af[mi] = *(const short8*)&As[(wm + mi * 16 + l15) * 32 + qd * 8];
#pragma unroll
    for (int ni = 0; ni < 4; ni++) bf[ni] = *(const short8*)&Bs[(wn + ni * 16 + l15) * 32 + qd * 8];
#pragma unroll
    for (int mi = 0; mi < 4; mi++)
#pragma unroll
      for (int ni = 0; ni < 4; ni++)
        acc[mi][ni] = __builtin_amdgcn_mfma_f32_16x16x32_bf16(af[mi], bf[ni], acc[mi][ni], 0, 0, 0);
  }

#pragma unroll
  for (int ni = 0; ni < 4; ni++) {
    const int c = n0 + wn + ni * 16 + l15;
    const float bv = (MODE == 4 || MODE == 5) ? 0.f : bias[c];
#pragma unroll
    for (int mi = 0; mi < 4; mi++) {
#pragma unroll
      for (int rg = 0; rg < 4; rg++) {
        const int r = m0 + wm + mi * 16 + qd * 4 + rg;
        float v = acc[mi][ni][rg] + bv;
        if (MODE == 0) {
          ((u16*)outp)[(size_t)r * N + c] = f2b(v);
          if (c >= 1024) {   // v columns: also write masked-v into padded conv input
            const int b = r / T_, t = r - b * T_;
            vmout[((size_t)b * TP_ + t + 5) * D_ + (c - 1024)] = f2b(v * masks[r]);
          }
        } else if (MODE == 1) {
          const size_t idx = (size_t)r * N + c;
          const int b = r / T_, t = r - b * T_;
          const float m  = masks[r];
          const float vm = b2f(vmp[((size_t)b * TP_ + t + 5) * D_ + c]);
          ((float*)outp)[idx] = v + (accin[idx] + vm) * m + add_f[idx];
        } else if (MODE == 2) {
          ((u16*)outp)[(size_t)r * N + c] = f2b(fmaxf(v, 0.f));
        } else if (MODE == 3) {
          const size_t idx = (size_t)r * N + c;
          ((float*)outp)[idx] = v + add_f[idx];
        } else if (MODE == 4) {
          atomicAdd((float*)outp + (size_t)r * N + c, v);
        } else {  // MODE 5
          const int t = r;
          if (t < T_) {
            const int b = zb >> 2, h = zb & 3;
            ((u16*)outp)[((size_t)b * T_ + t) * D_ + h * DK_ + c] = f2b(v);
          }
        }
      }
    }
  }
}

// =====================================================================
// Attention stage 1: P = softmax(mask(Q K^T / sqrt(dk)))  (normalized)
// grid (4 q-tiles of 64, 256 bh)
// =====================================================================
__global__ __launch_bounds__(256, 2)
void attn_scores(const u16* __restrict__ qkv, const float* __restrict__ masks,
                 u16* __restrict__ P)
{
  __shared__ u16 Qs[64][136];
  __shared__ u16 Ks[64][136];
  __shared__ float red0[4][64];
  __shared__ float red1[4][64];
  const int tid = threadIdx.x, lane = tid & 63, w = tid >> 6;
  const int l15 = lane & 15, qd = lane >> 4;
  const int bh = blockIdx.y, b = bh >> 2, h = bh & 3;
  const int q0 = blockIdx.x * 64;
  const uint4 uz = make_uint4(0, 0, 0, 0);

#pragma unroll
  for (int i = 0; i < 4; i++) {
    const int ch = tid + i * 256;
    const int row = ch >> 4, cg = (ch & 15) * 8;
    const int t = q0 + row;
    uint4 v = uz;
    if (t < T_) v = *(const uint4*)(qkv + ((size_t)b * T_ + t) * N3_ + h * DK_ + cg);
    *(uint4*)&Qs[row][cg] = v;
  }

  const f32x4 z4 = {0.f, 0.f, 0.f, 0.f};
  f32x4 acc[4][4];
#pragma unroll
  for (int i = 0; i < 4; i++)
#pragma unroll
    for (int j = 0; j < 4; j++) acc[i][j] = z4;

#pragma unroll
  for (int kc = 0; kc < 4; kc++) {
    __syncthreads();
#pragma unroll
    for (int i = 0; i < 4; i++) {
      const int ch = tid + i * 256;
      const int row = ch >> 4, cg = (ch & 15) * 8;
      const int t = kc * 64 + row;
      uint4 v = uz;
      if (t < T_) v = *(const uint4*)(qkv + ((size_t)b * T_ + t) * N3_ + D_ + h * DK_ + cg);
      *(uint4*)&Ks[row][cg] = v;
    }
    __syncthreads();
#pragma unroll
    for (int ks = 0; ks < 4; ks++) {
      short8 bf = *(const short8*)&Ks[w * 16 + l15][ks * 32 + qd * 8];
#pragma unroll
      for (int mi = 0; mi < 4; mi++) {
        short8 af = *(const short8*)&Qs[mi * 16 + l15][ks * 32 + qd * 8];
        acc[kc][mi] = __builtin_amdgcn_mfma_f32_16x16x32_bf16(af, bf, acc[kc][mi], 0, 0, 0);
      }
    }
  }

  const float scale = 0.08838834764831845f;  // 1/sqrt(128)
  const int colb = w * 16 + l15;
  bool valid[4];
#pragma unroll
  for (int kc = 0; kc < 4; kc++) {
    const int col = kc * 64 + colb;
    valid[kc] = (col < T_) && (masks[b * T_ + col] > 0.f);
  }

  float mx[4][4], sm[4][4];
#pragma unroll
  for (int mi = 0; mi < 4; mi++)
#pragma unroll
    for (int rg = 0; rg < 4; rg++) {
      float m = -1e30f;
#pragma unroll
      for (int kc = 0; kc < 4; kc++)
        if (valid[kc]) m = fmaxf(m, acc[kc][mi][rg] * scale);
      for (int d = 1; d < 16; d <<= 1) m = fmaxf(m, __shfl_xor(m, d, 64));
      mx[mi][rg] = m;
    }
  if (l15 == 0) {
#pragma unroll
    for (int mi = 0; mi < 4; mi++)
#pragma unroll
      for (int rg = 0; rg < 4; rg++) red0[w][mi * 16 + qd * 4 + rg] = mx[mi][rg];
  }
  __syncthreads();
#pragma unroll
  for (int mi = 0; mi < 4; mi++)
#pragma unroll
    for (int rg = 0; rg < 4; rg++) {
      const int r = mi * 16 + qd * 4 + rg;
      mx[mi][rg] = fmaxf(fmaxf(red0[0][r], red0[1][r]), fmaxf(red0[2][r], red0[3][r]));
    }
#pragma unroll
  for (int mi = 0; mi < 4; mi++)
#pragma unroll
    for (int rg = 0; rg < 4; rg++) {
      float s = 0.f;
#pragma unroll
      for (int kc = 0; kc < 4; kc++)
        if (valid[kc]) s += __expf(acc[kc][mi][rg] * scale - mx[mi][rg]);
      for (int d = 1; d < 16; d <<= 1) s += __shfl_xor(s, d, 64);
      sm[mi][rg] = s;
    }
  if (l15 == 0) {
#pragma unroll
    for (int mi = 0; mi < 4; mi++)
#pragma unroll
      for (int rg = 0; rg < 4; rg++) red1[w][mi * 16 + qd * 4 + rg] = sm[mi][rg];
  }
  __syncthreads();
#pragma unroll
  for (int mi = 0; mi < 4; mi++)
#pragma unroll
    for (int rg = 0; rg < 4; rg++) {
      const int r = mi * 16 + qd * 4 + rg;
      const int gq = q0 + r;
      const float inv = 1.f / (red1[0][r] + red1[1][r] + red1[2][r] + red1[3][r]);
#pragma unroll
      for (int kc = 0; kc < 4; kc++) {
        const int col = kc * 64 + colb;
        if (col < PW_) {
          const float p = valid[kc] ? __expf(acc[kc][mi][rg] * scale - mx[mi][rg]) * inv : 0.f;
          P[((size_t)bh * 256 + gq) * PW_ + col] = f2b(p);
        }
      }
    }
}

// ======================= small support kernels =======================
// LayerNorm: fp32 in -> bf16 out. 4 rows/block (one per wave).
__global__ __launch_bounds__(256)
void ln_k(const float* __restrict__ x, const float* __restrict__ wgt,
          const float* __restrict__ bia, u16* __restrict__ outp)
{
  const int lane = threadIdx.x & 63, wv = threadIdx.x >> 6;
  const size_t row = (size_t)blockIdx.x * 4 + wv;
  const float* rp = x + row * D_ + lane * 8;
  float v[8], s = 0.f, s2 = 0.f;
  float4 r0 = *(const float4*)rp;
  float4 r1 = *(const float4*)(rp + 4);
  v[0] = r0.x; v[1] = r0.y; v[2] = r0.z; v[3] = r0.w;
  v[4] = r1.x; v[5] = r1.y; v[6] = r1.z; v[7] = r1.w;
#pragma unroll
  for (int i = 0; i < 8; i++) { s += v[i]; s2 += v[i] * v[i]; }
  for (int d = 1; d < 64; d <<= 1) { s += __shfl_xor(s, d, 64); s2 += __shfl_xor(s2, d, 64); }
  const float mean = s * (1.f / 512.f);
  const float var  = s2 * (1.f / 512.f) - mean * mean;
  const float rs   = rsqrtf(var + 1e-5f);
  float4 w0 = *(const float4*)(wgt + lane * 8);
  float4 w1 = *(const float4*)(wgt + lane * 8 + 4);
  float4 b0 = *(const float4*)(bia + lane * 8);
  float4 b1 = *(const float4*)(bia + lane * 8 + 4);
  const float wv8[8] = {w0.x, w0.y, w0.z, w0.w, w1.x, w1.y, w1.z, w1.w};
  const float bv8[8] = {b0.x, b0.y, b0.z, b0.w, b1.x, b1.y, b1.z, b1.w};
  U8 o;
#pragma unroll
  for (int i = 0; i < 8; i++)
    o.u[i] = f2b((v[i] - mean) * rs * wv8[i] + bv8[i]);
  *(uint4*)(outp + row * D_ + lane * 8) = o.v;
}

// dst[n*K+k] (bf16) = src[k*N+n] (fp32).  K,N multiples of 32. grid (K/32, N/32)
__global__ void transpose_kn(const float* __restrict__ src, u16* __restrict__ dst,
                             int K, int N)
{
  __shared__ float tile[32][33];
  const int k0 = blockIdx.x * 32, n0 = blockIdx.y * 32;
  const int x = threadIdx.x & 31, y = threadIdx.x >> 5;  // y in 0..7
#pragma unroll
  for (int j = 0; j < 4; j++)
    tile[y + j * 8][x] = src[(size_t)(k0 + y + j * 8) * N + n0 + x];
  __syncthreads();
#pragma unroll
  for (int j = 0; j < 4; j++)
    dst[(size_t)(n0 + y + j * 8) * K + k0 + x] = f2b(tile[x][y + j * 8]);
}

// W2[o][tap*512+i] (bf16) = fsmn_w[o][i][tap] (fp32). one thread per (o,i).
__global__ void reorder_fsmn(const float* __restrict__ src, u16* __restrict__ dst)
{
  const int idx = blockIdx.x * 256 + threadIdx.x;   // o*512+i, < 262144
  const int o = idx >> 9, i = idx & 511;
  const float* s = src + (size_t)idx * 11;
#pragma unroll
  for (int tap = 0; tap < 11; ++tap)
    dst[(size_t)o * KC_ + tap * 512 + i] = f2b(s[tap]);
}

// Vt[bh][d][kv] = v[b, kv, h*128+d]  grid (7 kv-tiles, 4 d-tiles, 256 bh)
__global__ void fill_vt(const u16* __restrict__ qkv, u16* __restrict__ Vt)
{
  __shared__ u16 tile[32][33];
  const int bh = blockIdx.z, b = bh >> 2, h = bh & 3;
  const int kv0 = blockIdx.x * 32, d0 = blockIdx.y * 32;
  const int x = threadIdx.x & 31, y = threadIdx.x >> 5;
#pragma unroll
  for (int j = 0; j < 4; j++) {
    const int kv = kv0 + y + j * 8;
    u16 v = 0;
    if (kv < T_) v = qkv[((size_t)b * T_ + kv) * N3_ + 1024 + h * DK_ + d0 + x];
    tile[y + j * 8][x] = v;
  }
  __syncthreads();
#pragma unroll
  for (int j = 0; j < 4; j++) {
    const int d = d0 + y + j * 8;
    Vt[((size_t)bh * 128 + d) * PW_ + kv0 + x] = tile[x][y + j * 8];
  }
}

// =====================================================================
extern "C" void kernel_launch(void* const* d_in, const int* in_sizes, int n_in,
                              void* d_out, int out_size, void* d_ws, size_t ws_size,
                              hipStream_t stream)
{
  const float* x      = (const float*)d_in[0];
  const float* masks  = (const float*)d_in[1];
  const float* ln0_w  = (const float*)d_in[2];
  const float* ln0_b  = (const float*)d_in[3];
  const float* ln1_w  = (const float*)d_in[4];
  const float* ln1_b  = (const float*)d_in[5];
  const float* qkv_w  = (const float*)d_in[6];
  const float* qkv_b  = (const float*)d_in[7];
  const float* out_w  = (const float*)d_in[8];
  const float* out_b  = (const float*)d_in[9];
  const float* fsmn_w = (const float*)d_in[10];
  const float* w1     = (const float*)d_in[11];
  const float* b1     = (const float*)d_in[12];
  const float* w2     = (const float*)d_in[13];
  const float* b2     = (const float*)d_in[14];
  float* outp = (float*)d_out;
  u16* ws   = (u16*)d_ws;

  size_t off = 0;
  u16* qkv_wT = ws + off; off += (size_t)1536 * 512;
  u16* out_wT = ws + off; off += (size_t)512 * 512;
  u16* w1T    = ws + off; off += (size_t)2048 * 512;
  u16* w2T    = ws + off; off += (size_t)512 * 2048;
  u16* fsmnW2 = ws + off; off += (size_t)512 * KC_;       // (512o, 5632k)
  u16* slotA  = ws + off; off += (size_t)M_ * 512;        // h (ln0) -> ctx
  u16* qkvb   = ws + off; off += (size_t)M_ * 1536;       // qkv; later h1 + x1
  u16* vmpad  = ws + off; off += (size_t)B_ * TP_ * 512;  // padded v*mask
  u16* regionX= ws + off; off += (size_t)14680064 + 7340032 + 14286848;
  u16* Pbuf   = regionX;                                   // 256*256*224
  u16* Vtbuf  = regionX + 14680064;                        // 256*128*224
  float* convacc = (float*)(regionX + 14680064 + 7340032); // M*512 fp32
  u16* hid    = regionX;                                   // M*2048 (aliases; later)
  u16* h1     = qkvb;                                      // M*512 bf16
  float* x1   = (float*)(qkvb + (size_t)M_ * 512);         // M*512 fp32

  // zero conv accumulator + conv-input padding (re-done every call: ws is re-poisoned)
  hipMemsetAsync(convacc, 0, (size_t)M_ * 512 * sizeof(float), stream);
  hipMemsetAsync(vmpad, 0, (size_t)B_ * TP_ * 512 * sizeof(u16), stream);

  // weight prep (fp32 -> bf16, transposed to N x K)
  transpose_kn<<<dim3(512 / 32, 1536 / 32), 256, 0, stream>>>(qkv_w, qkv_wT, 512, 1536);
  transpose_kn<<<dim3(512 / 32, 512 / 32), 256, 0, stream>>>(out_w, out_wT, 512, 512);
  transpose_kn<<<dim3(512 / 32, 2048 / 32), 256, 0, stream>>>(w1, w1T, 512, 2048);
  transpose_kn<<<dim3(2048 / 32, 512 / 32), 256, 0, stream>>>(w2, w2T, 2048, 512);
  reorder_fsmn<<<262144 / 256, 256, 0, stream>>>(fsmn_w, fsmnW2);

  // ln0 -> h
  ln_k<<<M_ / 4, 256, 0, stream>>>(x, ln0_w, ln0_b, slotA);
  // qkv = h @ qkv_w + b  (bf16 out; v-cols also populate vmpad)
  gemm_u<0><<<dim3(M_ / 128, 1536 / 128, 1), 256, 0, stream>>>(
      slotA, 512, qkv_wT, 512, qkv_b, nullptr, nullptr, vmpad, nullptr, qkvb,
      1536, 512, masks);
  // fsmn conv: strided im2col GEMM, split-K x2, atomic fp32 accumulate
  gemm_u<4><<<dim3(M_ / 128, 512 / 128, 2), 256, 0, stream>>>(
      vmpad, 0, fsmnW2, KC_, nullptr, nullptr, nullptr, nullptr, nullptr, convacc,
      512, KH_, nullptr);
  // attention
  fill_vt<<<dim3(7, 4, 256), 256, 0, stream>>>(qkvb, Vtbuf);
  attn_scores<<<dim3(4, 256), 256, 0, stream>>>(qkvb, masks, Pbuf);
  gemm_u<5><<<dim3(2, 1, 256), 256, 0, stream>>>(
      Pbuf, PW_, Vtbuf, PW_, nullptr, nullptr, nullptr, nullptr, nullptr, slotA,
      128, PW_, nullptr);
  // x1 = x + ctx@out_w + out_b + (convacc+vm)*mask   (fp32 out)
  gemm_u<1><<<dim3(M_ / 128, 512 / 128, 1), 256, 0, stream>>>(
      slotA, 512, out_wT, 512, out_b, convacc, vmpad, nullptr, x, x1,
      512, 512, masks);
  // ffn
  ln_k<<<M_ / 4, 256, 0, stream>>>(x1, ln1_w, ln1_b, h1);
  gemm_u<2><<<dim3(M_ / 128, 2048 / 128, 1), 256, 0, stream>>>(
      h1, 512, w1T, 512, b1, nullptr, nullptr, nullptr, nullptr, hid,
      2048, 512, nullptr);
  gemm_u<3><<<dim3(M_ / 128, 512 / 128, 1), 256, 0, stream>>>(
      hid, 2048, w2T, 2048, b2, nullptr, nullptr, nullptr, x1, outp,
      512, 2048, nullptr);
}

// Round 5
// 541.258 us; speedup vs baseline: 1.1009x; 1.0126x over previous
//
#include <hip/hip_runtime.h>
#include <cstdint>

// ---- problem constants ----
#define B_   64
#define T_   218
#define TP_  228          // T + 2*PAD
#define D_   512
#define M_   13952        // B_*T_  (= 109*128, exact)
#define H_   4
#define DK_  128
#define PW_  224          // padded KV width for attention (7*32)
#define N3_  1536
#define DFF_ 2048
#define KC_  5632         // conv im2col K = 11*512
#define KH_  2816         // conv split-K half

static_assert(M_ % 128 == 0, "M tiles exact");

typedef unsigned short u16;   // raw bf16
using short8 = __attribute__((ext_vector_type(8))) short;
using f32x4  = __attribute__((ext_vector_type(4))) float;

__device__ __forceinline__ float b2f(u16 u) {
  union { float f; uint32_t i; } v; v.i = ((uint32_t)u) << 16; return v.f;
}
__device__ __forceinline__ u16 f2b(float f) {
  union { float f; uint32_t i; } v; v.f = f;
  uint32_t r = v.i + 0x7fffu + ((v.i >> 16) & 1u);
  return (u16)(r >> 16);
}
union U8 { uint4 v; u16 u[8]; };

// async global->LDS, 16 bytes per lane; LDS dest is wave-uniform base + lane*16
__device__ __forceinline__ void gll16(const u16* g, u16* l) {
  __builtin_amdgcn_global_load_lds(
      (const __attribute__((address_space(1))) unsigned int*)g,
      (__attribute__((address_space(3))) unsigned int*)l, 16, 0, 0);
}

// =====================================================================
// Unified 128x128 MFMA GEMM with global_load_lds staging (m97 structure).
// out[M,N] = A[M,K] (row stride sA) @ Bt[N,K]^T (row stride sB), + epilogue.
// MODE 0: bf16 out = acc+bias; v-cols also write vmpad (qkv)
// MODE 1: f32  out = acc+bias+(conv0+conv1+vm)*m+add_f (out-proj +fsmn +x)
// MODE 2: bf16 out = relu(acc+bias)                   (ffn1)
// MODE 3: f32  out = acc+bias+add_f                   (ffn2 +x1 -> d_out)
// MODE 4: conv im2col split-K: z=K-half, plain f32 store to half zb
// MODE 5: attn PV: z=bh, bf16 ctx out                 (P@V)
// =====================================================================
template<int MODE>
__global__ __launch_bounds__(256, 2)
void gemm_u(const u16* __restrict__ A, int sA, const u16* __restrict__ Bt, int sB,
            const float* __restrict__ bias, const float* __restrict__ conv0,
            const u16* __restrict__ vmp, u16* __restrict__ vmout,
            const float* __restrict__ add_f, void* __restrict__ outp,
            int N, int K, const float* __restrict__ masks)
{
  __shared__ u16 As[128 * 32];
  __shared__ u16 Bs[128 * 32];
  const int tid = threadIdx.x, lane = tid & 63, w = tid >> 6;
  const int wm = (w >> 1) * 64, wn = (w & 1) * 64;
  const int l15 = lane & 15, qd = lane >> 4;
  const int zb = blockIdx.z;
  const int m0 = blockIdx.x * 128, n0 = blockIdx.y * 128;

  const u16* Ab  = A;
  const u16* Btb = Bt;
  if (MODE == 5) { Ab = A + (size_t)zb * 256 * PW_; Btb = Bt + (size_t)zb * 128 * PW_; }

  // staging: wave w, issue j in {0,1}; lane covers row = j*64 + w*16 + lane/4,
  // 16B chunk = lane%4 of the 128x32 tile.
  const int rl = lane >> 2, ce = (lane & 3) * 8;
  const int r0 = m0 + w * 16 + rl, r1 = r0 + 64;
  size_t aoff0, aoff1, bkoff = 0;
  if (MODE == 4) {
    const int b0r = r0 / T_, t0r = r0 - b0r * T_;
    const int b1r = r1 / T_, t1r = r1 - b1r * T_;
    aoff0 = ((size_t)b0r * TP_ + t0r) * D_ + (size_t)zb * KH_;
    aoff1 = ((size_t)b1r * TP_ + t1r) * D_ + (size_t)zb * KH_;
    bkoff = (size_t)zb * KH_;
  } else {
    aoff0 = (size_t)r0 * sA;
    aoff1 = (size_t)r1 * sA;
  }
  const u16* ag0 = Ab + aoff0 + ce;
  const u16* ag1 = Ab + aoff1 + ce;
  const u16* bg0 = Btb + (size_t)(n0 + w * 16 + rl) * sB + bkoff + ce;
  const u16* bg1 = bg0 + (size_t)64 * sB;
  u16* lA0 = As + w * 512;
  u16* lA1 = As + 2048 + w * 512;
  u16* lB0 = Bs + w * 512;
  u16* lB1 = Bs + 2048 + w * 512;

  const f32x4 z4 = {0.f, 0.f, 0.f, 0.f};
  f32x4 acc[4][4];
#pragma unroll
  for (int i = 0; i < 4; i++)
#pragma unroll
    for (int j = 0; j < 4; j++) acc[i][j] = z4;

  for (int k0 = 0; k0 < K; k0 += 32) {
    __syncthreads();
    gll16(ag0 + k0, lA0);
    gll16(ag1 + k0, lA1);
    gll16(bg0 + k0, lB0);
    gll16(bg1 + k0, lB1);
    __syncthreads();
    short8 af[4], bf[4];
#pragma unroll
    for (int mi = 0; mi < 4; mi++) af[mi] = *(const short8*)&As[(wm + mi * 16 + l15) * 32 + qd * 8];
#pragma unroll
    for (int ni = 0; ni < 4; ni++) bf[ni] = *(const short8*)&Bs[(wn + ni * 16 + l15) * 32 + qd * 8];
#pragma unroll
    for (int mi = 0; mi < 4; mi++)
#pragma unroll
      for (int ni = 0; ni < 4; ni++)
        acc[mi][ni] = __builtin_amdgcn_mfma_f32_16x16x32_bf16(af[mi], bf[ni], acc[mi][ni], 0, 0, 0);
  }

#pragma unroll
  for (int ni = 0; ni < 4; ni++) {
    const int c = n0 + wn + ni * 16 + l15;
    const float bv = (MODE == 4 || MODE == 5) ? 0.f : bias[c];
#pragma unroll
    for (int mi = 0; mi < 4; mi++) {
#pragma unroll
      for (int rg = 0; rg < 4; rg++) {
        const int r = m0 + wm + mi * 16 + qd * 4 + rg;
        float v = acc[mi][ni][rg] + bv;
        if (MODE == 0) {
          ((u16*)outp)[(size_t)r * N + c] = f2b(v);
          if (c >= 1024) {   // v columns: also write masked-v into padded conv input
            const int b = r / T_, t = r - b * T_;
            vmout[((size_t)b * TP_ + t + 5) * D_ + (c - 1024)] = f2b(v * masks[r]);
          }
        } else if (MODE == 1) {
          const size_t idx = (size_t)r * N + c;
          const int b = r / T_, t = r - b * T_;
          const float m  = masks[r];
          const float cv = conv0[idx] + conv0[idx + (size_t)M_ * 512];
          const float vm = b2f(vmp[((size_t)b * TP_ + t + 5) * D_ + c]);
          ((float*)outp)[idx] = v + (cv + vm) * m + add_f[idx];
        } else if (MODE == 2) {
          ((u16*)outp)[(size_t)r * N + c] = f2b(fmaxf(v, 0.f));
        } else if (MODE == 3) {
          const size_t idx = (size_t)r * N + c;
          ((float*)outp)[idx] = v + add_f[idx];
        } else if (MODE == 4) {
          ((float*)outp)[(size_t)zb * ((size_t)M_ * 512) + (size_t)r * N + c] = v;
        } else {  // MODE 5
          const int t = r;
          if (t < T_) {
            const int b = zb >> 2, h = zb & 3;
            ((u16*)outp)[((size_t)b * T_ + t) * D_ + h * DK_ + c] = f2b(v);
          }
        }
      }
    }
  }
}

// =====================================================================
// Attention stage 1: P = softmax(mask(Q K^T / sqrt(dk)))  (normalized)
// grid (4 q-tiles of 64, 256 bh)
// =====================================================================
__global__ __launch_bounds__(256, 2)
void attn_scores(const u16* __restrict__ qkv, const float* __restrict__ masks,
                 u16* __restrict__ P)
{
  __shared__ u16 Qs[64][136];
  __shared__ u16 Ks[64][136];
  __shared__ float red0[4][64];
  __shared__ float red1[4][64];
  const int tid = threadIdx.x, lane = tid & 63, w = tid >> 6;
  const int l15 = lane & 15, qd = lane >> 4;
  const int bh = blockIdx.y, b = bh >> 2, h = bh & 3;
  const int q0 = blockIdx.x * 64;
  const uint4 uz = make_uint4(0, 0, 0, 0);

#pragma unroll
  for (int i = 0; i < 4; i++) {
    const int ch = tid + i * 256;
    const int row = ch >> 4, cg = (ch & 15) * 8;
    const int t = q0 + row;
    uint4 v = uz;
    if (t < T_) v = *(const uint4*)(qkv + ((size_t)b * T_ + t) * N3_ + h * DK_ + cg);
    *(uint4*)&Qs[row][cg] = v;
  }

  const f32x4 z4 = {0.f, 0.f, 0.f, 0.f};
  f32x4 acc[4][4];
#pragma unroll
  for (int i = 0; i < 4; i++)
#pragma unroll
    for (int j = 0; j < 4; j++) acc[i][j] = z4;

#pragma unroll
  for (int kc = 0; kc < 4; kc++) {
    __syncthreads();
#pragma unroll
    for (int i = 0; i < 4; i++) {
      const int ch = tid + i * 256;
      const int row = ch >> 4, cg = (ch & 15) * 8;
      const int t = kc * 64 + row;
      uint4 v = uz;
      if (t < T_) v = *(const uint4*)(qkv + ((size_t)b * T_ + t) * N3_ + D_ + h * DK_ + cg);
      *(uint4*)&Ks[row][cg] = v;
    }
    __syncthreads();
#pragma unroll
    for (int ks = 0; ks < 4; ks++) {
      short8 bf = *(const short8*)&Ks[w * 16 + l15][ks * 32 + qd * 8];
#pragma unroll
      for (int mi = 0; mi < 4; mi++) {
        short8 af = *(const short8*)&Qs[mi * 16 + l15][ks * 32 + qd * 8];
        acc[kc][mi] = __builtin_amdgcn_mfma_f32_16x16x32_bf16(af, bf, acc[kc][mi], 0, 0, 0);
      }
    }
  }

  const float scale = 0.08838834764831845f;  // 1/sqrt(128)
  const int colb = w * 16 + l15;
  bool valid[4];
#pragma unroll
  for (int kc = 0; kc < 4; kc++) {
    const int col = kc * 64 + colb;
    valid[kc] = (col < T_) && (masks[b * T_ + col] > 0.f);
  }

  float mx[4][4], sm[4][4];
#pragma unroll
  for (int mi = 0; mi < 4; mi++)
#pragma unroll
    for (int rg = 0; rg < 4; rg++) {
      float m = -1e30f;
#pragma unroll
      for (int kc = 0; kc < 4; kc++)
        if (valid[kc]) m = fmaxf(m, acc[kc][mi][rg] * scale);
      for (int d = 1; d < 16; d <<= 1) m = fmaxf(m, __shfl_xor(m, d, 64));
      mx[mi][rg] = m;
    }
  if (l15 == 0) {
#pragma unroll
    for (int mi = 0; mi < 4; mi++)
#pragma unroll
      for (int rg = 0; rg < 4; rg++) red0[w][mi * 16 + qd * 4 + rg] = mx[mi][rg];
  }
  __syncthreads();
#pragma unroll
  for (int mi = 0; mi < 4; mi++)
#pragma unroll
    for (int rg = 0; rg < 4; rg++) {
      const int r = mi * 16 + qd * 4 + rg;
      mx[mi][rg] = fmaxf(fmaxf(red0[0][r], red0[1][r]), fmaxf(red0[2][r], red0[3][r]));
    }
#pragma unroll
  for (int mi = 0; mi < 4; mi++)
#pragma unroll
    for (int rg = 0; rg < 4; rg++) {
      float s = 0.f;
#pragma unroll
      for (int kc = 0; kc < 4; kc++)
        if (valid[kc]) s += __expf(acc[kc][mi][rg] * scale - mx[mi][rg]);
      for (int d = 1; d < 16; d <<= 1) s += __shfl_xor(s, d, 64);
      sm[mi][rg] = s;
    }
  if (l15 == 0) {
#pragma unroll
    for (int mi = 0; mi < 4; mi++)
#pragma unroll
      for (int rg = 0; rg < 4; rg++) red1[w][mi * 16 + qd * 4 + rg] = sm[mi][rg];
  }
  __syncthreads();
#pragma unroll
  for (int mi = 0; mi < 4; mi++)
#pragma unroll
    for (int rg = 0; rg < 4; rg++) {
      const int r = mi * 16 + qd * 4 + rg;
      const int gq = q0 + r;
      const float inv = 1.f / (red1[0][r] + red1[1][r] + red1[2][r] + red1[3][r]);
#pragma unroll
      for (int kc = 0; kc < 4; kc++) {
        const int col = kc * 64 + colb;
        if (col < PW_) {
          const float p = valid[kc] ? __expf(acc[kc][mi][rg] * scale - mx[mi][rg]) * inv : 0.f;
          P[((size_t)bh * 256 + gq) * PW_ + col] = f2b(p);
        }
      }
    }
}

// ======================= small support kernels =======================
// LayerNorm: fp32 in -> bf16 out. 4 rows/block (one per wave).
__global__ __launch_bounds__(256)
void ln_k(const float* __restrict__ x, const float* __restrict__ wgt,
          const float* __restrict__ bia, u16* __restrict__ outp)
{
  const int lane = threadIdx.x & 63, wv = threadIdx.x >> 6;
  const size_t row = (size_t)blockIdx.x * 4 + wv;
  const float* rp = x + row * D_ + lane * 8;
  float v[8], s = 0.f, s2 = 0.f;
  float4 r0 = *(const float4*)rp;
  float4 r1 = *(const float4*)(rp + 4);
  v[0] = r0.x; v[1] = r0.y; v[2] = r0.z; v[3] = r0.w;
  v[4] = r1.x; v[5] = r1.y; v[6] = r1.z; v[7] = r1.w;
#pragma unroll
  for (int i = 0; i < 8; i++) { s += v[i]; s2 += v[i] * v[i]; }
  for (int d = 1; d < 64; d <<= 1) { s += __shfl_xor(s, d, 64); s2 += __shfl_xor(s2, d, 64); }
  const float mean = s * (1.f / 512.f);
  const float var  = s2 * (1.f / 512.f) - mean * mean;
  const float rs   = rsqrtf(var + 1e-5f);
  float4 w0 = *(const float4*)(wgt + lane * 8);
  float4 w1 = *(const float4*)(wgt + lane * 8 + 4);
  float4 b0 = *(const float4*)(bia + lane * 8);
  float4 b1 = *(const float4*)(bia + lane * 8 + 4);
  const float wv8[8] = {w0.x, w0.y, w0.z, w0.w, w1.x, w1.y, w1.z, w1.w};
  const float bv8[8] = {b0.x, b0.y, b0.z, b0.w, b1.x, b1.y, b1.z, b1.w};
  U8 o;
#pragma unroll
  for (int i = 0; i < 8; i++)
    o.u[i] = f2b((v[i] - mean) * rs * wv8[i] + bv8[i]);
  *(uint4*)(outp + row * D_ + lane * 8) = o.v;
}

// =====================================================================
// Merged prep: all 4 weight transposes (fp32 KxN -> bf16 NxK), fsmn
// reorder (o,i,tap)->(o, tap*512+i), and vmpad pad-row zeroing.
// grid: [0,768) qkv_w | [768,1024) out_w | [1024,2048) w1 | [2048,3072) w2
//       [3072,4096) fsmn reorder | [4096,4256) vmpad pad rows
// =====================================================================
__global__ __launch_bounds__(256)
void prep_all(const float* __restrict__ qkv_w, const float* __restrict__ out_w,
              const float* __restrict__ w1, const float* __restrict__ w2,
              const float* __restrict__ fsmn_w,
              u16* __restrict__ qkv_wT, u16* __restrict__ out_wT,
              u16* __restrict__ w1T, u16* __restrict__ w2T,
              u16* __restrict__ fsmnW2, u16* __restrict__ vmpad)
{
  const int bid = blockIdx.x;
  if (bid < 3072) {
    const float* src; u16* dst; int K, N, tb;
    if (bid < 768)       { src = qkv_w; dst = qkv_wT; K = 512;  N = 1536; tb = bid; }
    else if (bid < 1024) { src = out_w; dst = out_wT; K = 512;  N = 512;  tb = bid - 768; }
    else if (bid < 2048) { src = w1;    dst = w1T;    K = 512;  N = 2048; tb = bid - 1024; }
    else                 { src = w2;    dst = w2T;    K = 2048; N = 512;  tb = bid - 2048; }
    const int ktiles = K / 32;
    const int k0 = (tb % ktiles) * 32, n0 = (tb / ktiles) * 32;
    __shared__ float tile[32][33];
    const int x = threadIdx.x & 31, y = threadIdx.x >> 5;
#pragma unroll
    for (int j = 0; j < 4; j++)
      tile[y + j * 8][x] = src[(size_t)(k0 + y + j * 8) * N + n0 + x];
    __syncthreads();
#pragma unroll
    for (int j = 0; j < 4; j++)
      dst[(size_t)(n0 + y + j * 8) * K + k0 + x] = f2b(tile[x][y + j * 8]);
  } else if (bid < 4096) {
    const int idx = (bid - 3072) * 256 + threadIdx.x;   // o*512+i
    const int o = idx >> 9, i = idx & 511;
    const float* s = fsmn_w + (size_t)idx * 11;
#pragma unroll
    for (int tap = 0; tap < 11; ++tap)
      fsmnW2[(size_t)o * KC_ + tap * 512 + i] = f2b(s[tap]);
  } else {
    // zero the 10 pad rows per batch (rows 0..4 and 223..227 of each 228-row slab)
    const int e8 = (bid - 4096) * 256 + threadIdx.x;  // uint4 index, < 40960
    const int e  = e8 * 8;
    const int c  = e & 511;
    const int pr = e >> 9;              // 0..639
    const int b  = pr / 10, j = pr % 10;
    const int row = (j < 5) ? j : (218 + j);   // 0..4 or 223..227
    *(uint4*)(vmpad + ((size_t)b * TP_ + row) * D_ + c) = make_uint4(0, 0, 0, 0);
  }
}

// Vt[bh][d][kv] = v[b, kv, h*128+d]  grid (7 kv-tiles, 4 d-tiles, 256 bh)
__global__ void fill_vt(const u16* __restrict__ qkv, u16* __restrict__ Vt)
{
  __shared__ u16 tile[32][33];
  const int bh = blockIdx.z, b = bh >> 2, h = bh & 3;
  const int kv0 = blockIdx.x * 32, d0 = blockIdx.y * 32;
  const int x = threadIdx.x & 31, y = threadIdx.x >> 5;
#pragma unroll
  for (int j = 0; j < 4; j++) {
    const int kv = kv0 + y + j * 8;
    u16 v = 0;
    if (kv < T_) v = qkv[((size_t)b * T_ + kv) * N3_ + 1024 + h * DK_ + d0 + x];
    tile[y + j * 8][x] = v;
  }
  __syncthreads();
#pragma unroll
  for (int j = 0; j < 4; j++) {
    const int d = d0 + y + j * 8;
    Vt[((size_t)bh * 128 + d) * PW_ + kv0 + x] = tile[x][y + j * 8];
  }
}

// =====================================================================
extern "C" void kernel_launch(void* const* d_in, const int* in_sizes, int n_in,
                              void* d_out, int out_size, void* d_ws, size_t ws_size,
                              hipStream_t stream)
{
  const float* x      = (const float*)d_in[0];
  const float* masks  = (const float*)d_in[1];
  const float* ln0_w  = (const float*)d_in[2];
  const float* ln0_b  = (const float*)d_in[3];
  const float* ln1_w  = (const float*)d_in[4];
  const float* ln1_b  = (const float*)d_in[5];
  const float* qkv_w  = (const float*)d_in[6];
  const float* qkv_b  = (const float*)d_in[7];
  const float* out_w  = (const float*)d_in[8];
  const float* out_b  = (const float*)d_in[9];
  const float* fsmn_w = (const float*)d_in[10];
  const float* w1     = (const float*)d_in[11];
  const float* b1     = (const float*)d_in[12];
  const float* w2     = (const float*)d_in[13];
  const float* b2     = (const float*)d_in[14];
  float* outp = (float*)d_out;
  u16* ws   = (u16*)d_ws;

  size_t off = 0;
  u16* qkv_wT = ws + off; off += (size_t)1536 * 512;
  u16* out_wT = ws + off; off += (size_t)512 * 512;
  u16* w1T    = ws + off; off += (size_t)2048 * 512;
  u16* w2T    = ws + off; off += (size_t)512 * 2048;
  u16* fsmnW2 = ws + off; off += (size_t)512 * KC_;       // (512o, 5632k)
  u16* slotA  = ws + off; off += (size_t)M_ * 512;        // h (ln0) -> ctx
  u16* qkvb   = ws + off; off += (size_t)M_ * 1536;       // qkv; later h1 + x1
  u16* vmpad  = ws + off; off += (size_t)B_ * TP_ * 512;  // padded v*mask
  u16* regionX= ws + off;
  // regionX layout: Pbuf (14.68M u16) + Vtbuf (7.34M) + convacc (2*M*512 f32 =
  // 28.57M u16-units). hid (M*2048 u16 = 28.57M) aliases the front of regionX
  // after Pbuf/Vtbuf/convacc are consumed (convacc dead after out-proj, which
  // precedes ffn1).
  u16* Pbuf   = regionX;                                   // 256*256*224
  u16* Vtbuf  = regionX + (size_t)256 * 256 * PW_;         // 256*128*224
  float* convacc = (float*)(Vtbuf + (size_t)256 * 128 * PW_); // 2 * M*512 fp32
  u16* hid    = regionX;                                   // M*2048 bf16
  u16* h1     = qkvb;                                      // M*512 bf16
  float* x1   = (float*)(qkvb + (size_t)M_ * 512);         // M*512 fp32

  // weight prep + vmpad pad-row zeroing, one launch
  prep_all<<<4256, 256, 0, stream>>>(qkv_w, out_w, w1, w2, fsmn_w,
                                     qkv_wT, out_wT, w1T, w2T, fsmnW2, vmpad);
  // ln0 -> h
  ln_k<<<M_ / 4, 256, 0, stream>>>(x, ln0_w, ln0_b, slotA);
  // qkv = h @ qkv_w + b  (bf16 out; v-cols also populate vmpad interior)
  gemm_u<0><<<dim3(M_ / 128, 1536 / 128, 1), 256, 0, stream>>>(
      slotA, 512, qkv_wT, 512, qkv_b, nullptr, nullptr, vmpad, nullptr, qkvb,
      1536, 512, masks);
  // fsmn conv: strided im2col GEMM, split-K x2, plain f32 stores per half
  gemm_u<4><<<dim3(M_ / 128, 512 / 128, 2), 256, 0, stream>>>(
      vmpad, 0, fsmnW2, KC_, nullptr, nullptr, nullptr, nullptr, nullptr, convacc,
      512, KH_, nullptr);
  // attention
  fill_vt<<<dim3(7, 4, 256), 256, 0, stream>>>(qkvb, Vtbuf);
  attn_scores<<<dim3(4, 256), 256, 0, stream>>>(qkvb, masks, Pbuf);
  gemm_u<5><<<dim3(2, 1, 256), 256, 0, stream>>>(
      Pbuf, PW_, Vtbuf, PW_, nullptr, nullptr, nullptr, nullptr, nullptr, slotA,
      128, PW_, nullptr);
  // x1 = x + ctx@out_w + out_b + (conv0+conv1+vm)*mask   (fp32 out)
  gemm_u<1><<<dim3(M_ / 128, 512 / 128, 1), 256, 0, stream>>>(
      slotA, 512, out_wT, 512, out_b, convacc, vmpad, nullptr, x, x1,
      512, 512, masks);
  // ffn
  ln_k<<<M_ / 4, 256, 0, stream>>>(x1, ln1_w, ln1_b, h1);
  gemm_u<2><<<dim3(M_ / 128, 2048 / 128, 1), 256, 0, stream>>>(
      h1, 512, w1T, 512, b1, nullptr, nullptr, nullptr, nullptr, hid,
      2048, 512, nullptr);
  gemm_u<3><<<dim3(M_ / 128, 512 / 128, 1), 256, 0, stream>>>(
      hid, 2048, w2T, 2048, b2, nullptr, nullptr, nullptr, x1, outp,
      512, 2048, nullptr);
}

// Round 6
// 511.915 us; speedup vs baseline: 1.1640x; 1.0573x over previous
//
#include <hip/hip_runtime.h>
#include <cstdint>

// ---- problem constants ----
#define B_   64
#define T_   218
#define TP_  228          // T + 2*PAD
#define D_   512
#define M_   13952        // B_*T_  (= 109*128, exact)
#define MT_  109          // m-tiles
#define H_   4
#define DK_  128
#define PW_  224          // padded KV width for attention (7*32)
#define N3_  1536
#define DFF_ 2048
#define KC_  5632         // conv im2col K = 11*512
#define KH_  2816         // conv split-K half

typedef unsigned short u16;   // raw bf16
using short8 = __attribute__((ext_vector_type(8))) short;
using f32x4  = __attribute__((ext_vector_type(4))) float;

__device__ __forceinline__ float b2f(u16 u) {
  union { float f; uint32_t i; } v; v.i = ((uint32_t)u) << 16; return v.f;
}
__device__ __forceinline__ u16 f2b(float f) {
  union { float f; uint32_t i; } v; v.f = f;
  uint32_t r = v.i + 0x7fffu + ((v.i >> 16) & 1u);
  return (u16)(r >> 16);
}
union U8 { uint4 v; u16 u[8]; };

// async global->LDS, 16 bytes per lane; LDS dest is wave-uniform base + lane*16
__device__ __forceinline__ void gll16(const u16* g, u16* l) {
  __builtin_amdgcn_global_load_lds(
      (const __attribute__((address_space(1))) unsigned int*)g,
      (__attribute__((address_space(3))) unsigned int*)l, 16, 0, 0);
}

// =====================================================================
// Unified 128x128 MFMA GEMM with global_load_lds staging (m97 structure)
// and XCD-aware 1D block swizzle (blockIdx%8 -> XCD heuristic).
// out[M,N] = A[M,K] (row stride sA) @ Bt[N,K]^T (row stride sB), + epilogue.
// MODE 0: bf16 out = acc+bias; v-cols also write vmpad (qkv)
// MODE 1: f32  out = acc+bias+(conv0+conv1+vm)*m+add_f (out-proj +fsmn +x)
// MODE 2: bf16 out = relu(acc+bias)                   (ffn1)
// MODE 3: f32  out = acc+bias+add_f                   (ffn2 +x1 -> d_out)
// MODE 4: conv im2col split-K: XCD owns (n,z); plain f32 store to half z
// MODE 5: attn PV: 3D grid, z=bh, bf16 ctx out        (P@V)
// Weight-stationary swizzle (modes 0-3): XCD j gets m-tiles m%8==j, n fastest
//   -> per-XCD L2 keeps full B + current A-tile.
// =====================================================================
template<int MODE>
__global__ __launch_bounds__(256, 2)
void gemm_u(const u16* __restrict__ A, int sA, const u16* __restrict__ Bt, int sB,
            const float* __restrict__ bias, const float* __restrict__ conv0,
            const u16* __restrict__ vmp, u16* __restrict__ vmout,
            const float* __restrict__ add_f, void* __restrict__ outp,
            int N, int K, int ntc, const float* __restrict__ masks)
{
  __shared__ u16 As[128 * 32];
  __shared__ u16 Bs[128 * 32];

  // ---- block decode (1D swizzled except MODE 5) ----
  int mt, nt, zb = 0;
  if (MODE == 5) {
    mt = blockIdx.x; nt = 0; zb = blockIdx.z;
  } else if (MODE == 4) {
    const int j = blockIdx.x & 7;      // (n,z) combo -> XCD j
    nt = j & 3; zb = j >> 2;
    mt = blockIdx.x >> 3;              // m streams within XCD
  } else {
    const int xcd = blockIdx.x & 7;
    const int lin = blockIdx.x >> 3;
    nt = lin % ntc;                    // n fastest: A-tile reuse in L2
    mt = xcd + 8 * (lin / ntc);        // m%8 == xcd: B pinned per XCD
    if (mt >= MT_) return;
  }
  const int m0 = mt * 128, n0 = nt * 128;

  const int tid = threadIdx.x, lane = tid & 63, w = tid >> 6;
  const int wm = (w >> 1) * 64, wn = (w & 1) * 64;
  const int l15 = lane & 15, qd = lane >> 4;

  const u16* Ab  = A;
  const u16* Btb = Bt;
  if (MODE == 5) { Ab = A + (size_t)zb * 256 * PW_; Btb = Bt + (size_t)zb * 128 * PW_; }

  // staging: wave w, issue j in {0,1}; lane covers row = j*64 + w*16 + lane/4,
  // 16B chunk = lane%4 of the 128x32 tile.
  const int rl = lane >> 2, ce = (lane & 3) * 8;
  const int r0 = m0 + w * 16 + rl, r1 = r0 + 64;
  size_t aoff0, aoff1, bkoff = 0;
  if (MODE == 4) {
    const int b0r = r0 / T_, t0r = r0 - b0r * T_;
    const int b1r = r1 / T_, t1r = r1 - b1r * T_;
    aoff0 = ((size_t)b0r * TP_ + t0r) * D_ + (size_t)zb * KH_;
    aoff1 = ((size_t)b1r * TP_ + t1r) * D_ + (size_t)zb * KH_;
    bkoff = (size_t)zb * KH_;
  } else {
    aoff0 = (size_t)r0 * sA;
    aoff1 = (size_t)r1 * sA;
  }
  const u16* ag0 = Ab + aoff0 + ce;
  const u16* ag1 = Ab + aoff1 + ce;
  const u16* bg0 = Btb + (size_t)(n0 + w * 16 + rl) * sB + bkoff + ce;
  const u16* bg1 = bg0 + (size_t)64 * sB;
  u16* lA0 = As + w * 512;
  u16* lA1 = As + 2048 + w * 512;
  u16* lB0 = Bs + w * 512;
  u16* lB1 = Bs + 2048 + w * 512;

  const f32x4 z4 = {0.f, 0.f, 0.f, 0.f};
  f32x4 acc[4][4];
#pragma unroll
  for (int i = 0; i < 4; i++)
#pragma unroll
    for (int j = 0; j < 4; j++) acc[i][j] = z4;

  for (int k0 = 0; k0 < K; k0 += 32) {
    __syncthreads();
    gll16(ag0 + k0, lA0);
    gll16(ag1 + k0, lA1);
    gll16(bg0 + k0, lB0);
    gll16(bg1 + k0, lB1);
    __syncthreads();
    short8 af[4], bf[4];
#pragma unroll
    for (int mi = 0; mi < 4; mi++) af[mi] = *(const short8*)&As[(wm + mi * 16 + l15) * 32 + qd * 8];
#pragma unroll
    for (int ni = 0; ni < 4; ni++) bf[ni] = *(const short8*)&Bs[(wn + ni * 16 + l15) * 32 + qd * 8];
#pragma unroll
    for (int mi = 0; mi < 4; mi++)
#pragma unroll
      for (int ni = 0; ni < 4; ni++)
        acc[mi][ni] = __builtin_amdgcn_mfma_f32_16x16x32_bf16(af[mi], bf[ni], acc[mi][ni], 0, 0, 0);
  }

#pragma unroll
  for (int ni = 0; ni < 4; ni++) {
    const int c = n0 + wn + ni * 16 + l15;
    const float bv = (MODE == 4 || MODE == 5) ? 0.f : bias[c];
#pragma unroll
    for (int mi = 0; mi < 4; mi++) {
#pragma unroll
      for (int rg = 0; rg < 4; rg++) {
        const int r = m0 + wm + mi * 16 + qd * 4 + rg;
        float v = acc[mi][ni][rg] + bv;
        if (MODE == 0) {
          ((u16*)outp)[(size_t)r * N + c] = f2b(v);
          if (c >= 1024) {   // v columns: also write masked-v into padded conv input
            const int b = r / T_, t = r - b * T_;
            vmout[((size_t)b * TP_ + t + 5) * D_ + (c - 1024)] = f2b(v * masks[r]);
          }
        } else if (MODE == 1) {
          const size_t idx = (size_t)r * N + c;
          const int b = r / T_, t = r - b * T_;
          const float m  = masks[r];
          const float cv = conv0[idx] + conv0[idx + (size_t)M_ * 512];
          const float vm = b2f(vmp[((size_t)b * TP_ + t + 5) * D_ + c]);
          ((float*)outp)[idx] = v + (cv + vm) * m + add_f[idx];
        } else if (MODE == 2) {
          ((u16*)outp)[(size_t)r * N + c] = f2b(fmaxf(v, 0.f));
        } else if (MODE == 3) {
          const size_t idx = (size_t)r * N + c;
          ((float*)outp)[idx] = v + add_f[idx];
        } else if (MODE == 4) {
          ((float*)outp)[(size_t)zb * ((size_t)M_ * 512) + (size_t)r * N + c] = v;
        } else {  // MODE 5
          const int t = r;
          if (t < T_) {
            const int b = zb >> 2, h = zb & 3;
            ((u16*)outp)[((size_t)b * T_ + t) * D_ + h * DK_ + c] = f2b(v);
          }
        }
      }
    }
  }
}

// =====================================================================
// Attention stage 1: P = softmax(mask(Q K^T / sqrt(dk)))  (normalized)
// grid (4 q-tiles of 64, 256 bh)
// =====================================================================
__global__ __launch_bounds__(256, 2)
void attn_scores(const u16* __restrict__ qkv, const float* __restrict__ masks,
                 u16* __restrict__ P)
{
  __shared__ u16 Qs[64][136];
  __shared__ u16 Ks[64][136];
  __shared__ float red0[4][64];
  __shared__ float red1[4][64];
  const int tid = threadIdx.x, lane = tid & 63, w = tid >> 6;
  const int l15 = lane & 15, qd = lane >> 4;
  const int bh = blockIdx.y, b = bh >> 2, h = bh & 3;
  const int q0 = blockIdx.x * 64;
  const uint4 uz = make_uint4(0, 0, 0, 0);

#pragma unroll
  for (int i = 0; i < 4; i++) {
    const int ch = tid + i * 256;
    const int row = ch >> 4, cg = (ch & 15) * 8;
    const int t = q0 + row;
    uint4 v = uz;
    if (t < T_) v = *(const uint4*)(qkv + ((size_t)b * T_ + t) * N3_ + h * DK_ + cg);
    *(uint4*)&Qs[row][cg] = v;
  }

  const f32x4 z4 = {0.f, 0.f, 0.f, 0.f};
  f32x4 acc[4][4];
#pragma unroll
  for (int i = 0; i < 4; i++)
#pragma unroll
    for (int j = 0; j < 4; j++) acc[i][j] = z4;

#pragma unroll
  for (int kc = 0; kc < 4; kc++) {
    __syncthreads();
#pragma unroll
    for (int i = 0; i < 4; i++) {
      const int ch = tid + i * 256;
      const int row = ch >> 4, cg = (ch & 15) * 8;
      const int t = kc * 64 + row;
      uint4 v = uz;
      if (t < T_) v = *(const uint4*)(qkv + ((size_t)b * T_ + t) * N3_ + D_ + h * DK_ + cg);
      *(uint4*)&Ks[row][cg] = v;
    }
    __syncthreads();
#pragma unroll
    for (int ks = 0; ks < 4; ks++) {
      short8 bf = *(const short8*)&Ks[w * 16 + l15][ks * 32 + qd * 8];
#pragma unroll
      for (int mi = 0; mi < 4; mi++) {
        short8 af = *(const short8*)&Qs[mi * 16 + l15][ks * 32 + qd * 8];
        acc[kc][mi] = __builtin_amdgcn_mfma_f32_16x16x32_bf16(af, bf, acc[kc][mi], 0, 0, 0);
      }
    }
  }

  const float scale = 0.08838834764831845f;  // 1/sqrt(128)
  const int colb = w * 16 + l15;
  bool valid[4];
#pragma unroll
  for (int kc = 0; kc < 4; kc++) {
    const int col = kc * 64 + colb;
    valid[kc] = (col < T_) && (masks[b * T_ + col] > 0.f);
  }

  float mx[4][4], sm[4][4];
#pragma unroll
  for (int mi = 0; mi < 4; mi++)
#pragma unroll
    for (int rg = 0; rg < 4; rg++) {
      float m = -1e30f;
#pragma unroll
      for (int kc = 0; kc < 4; kc++)
        if (valid[kc]) m = fmaxf(m, acc[kc][mi][rg] * scale);
      for (int d = 1; d < 16; d <<= 1) m = fmaxf(m, __shfl_xor(m, d, 64));
      mx[mi][rg] = m;
    }
  if (l15 == 0) {
#pragma unroll
    for (int mi = 0; mi < 4; mi++)
#pragma unroll
      for (int rg = 0; rg < 4; rg++) red0[w][mi * 16 + qd * 4 + rg] = mx[mi][rg];
  }
  __syncthreads();
#pragma unroll
  for (int mi = 0; mi < 4; mi++)
#pragma unroll
    for (int rg = 0; rg < 4; rg++) {
      const int r = mi * 16 + qd * 4 + rg;
      mx[mi][rg] = fmaxf(fmaxf(red0[0][r], red0[1][r]), fmaxf(red0[2][r], red0[3][r]));
    }
#pragma unroll
  for (int mi = 0; mi < 4; mi++)
#pragma unroll
    for (int rg = 0; rg < 4; rg++) {
      float s = 0.f;
#pragma unroll
      for (int kc = 0; kc < 4; kc++)
        if (valid[kc]) s += __expf(acc[kc][mi][rg] * scale - mx[mi][rg]);
      for (int d = 1; d < 16; d <<= 1) s += __shfl_xor(s, d, 64);
      sm[mi][rg] = s;
    }
  if (l15 == 0) {
#pragma unroll
    for (int mi = 0; mi < 4; mi++)
#pragma unroll
      for (int rg = 0; rg < 4; rg++) red1[w][mi * 16 + qd * 4 + rg] = sm[mi][rg];
  }
  __syncthreads();
#pragma unroll
  for (int mi = 0; mi < 4; mi++)
#pragma unroll
    for (int rg = 0; rg < 4; rg++) {
      const int r = mi * 16 + qd * 4 + rg;
      const int gq = q0 + r;
      const float inv = 1.f / (red1[0][r] + red1[1][r] + red1[2][r] + red1[3][r]);
#pragma unroll
      for (int kc = 0; kc < 4; kc++) {
        const int col = kc * 64 + colb;
        if (col < PW_) {
          const float p = valid[kc] ? __expf(acc[kc][mi][rg] * scale - mx[mi][rg]) * inv : 0.f;
          P[((size_t)bh * 256 + gq) * PW_ + col] = f2b(p);
        }
      }
    }
}

// ======================= small support kernels =======================
// LayerNorm: fp32 in -> bf16 out. 4 rows/block (one per wave).
__global__ __launch_bounds__(256)
void ln_k(const float* __restrict__ x, const float* __restrict__ wgt,
          const float* __restrict__ bia, u16* __restrict__ outp)
{
  const int lane = threadIdx.x & 63, wv = threadIdx.x >> 6;
  const size_t row = (size_t)blockIdx.x * 4 + wv;
  const float* rp = x + row * D_ + lane * 8;
  float v[8], s = 0.f, s2 = 0.f;
  float4 r0 = *(const float4*)rp;
  float4 r1 = *(const float4*)(rp + 4);
  v[0] = r0.x; v[1] = r0.y; v[2] = r0.z; v[3] = r0.w;
  v[4] = r1.x; v[5] = r1.y; v[6] = r1.z; v[7] = r1.w;
#pragma unroll
  for (int i = 0; i < 8; i++) { s += v[i]; s2 += v[i] * v[i]; }
  for (int d = 1; d < 64; d <<= 1) { s += __shfl_xor(s, d, 64); s2 += __shfl_xor(s2, d, 64); }
  const float mean = s * (1.f / 512.f);
  const float var  = s2 * (1.f / 512.f) - mean * mean;
  const float rs   = rsqrtf(var + 1e-5f);
  float4 w0 = *(const float4*)(wgt + lane * 8);
  float4 w1 = *(const float4*)(wgt + lane * 8 + 4);
  float4 b0 = *(const float4*)(bia + lane * 8);
  float4 b1 = *(const float4*)(bia + lane * 8 + 4);
  const float wv8[8] = {w0.x, w0.y, w0.z, w0.w, w1.x, w1.y, w1.z, w1.w};
  const float bv8[8] = {b0.x, b0.y, b0.z, b0.w, b1.x, b1.y, b1.z, b1.w};
  U8 o;
#pragma unroll
  for (int i = 0; i < 8; i++)
    o.u[i] = f2b((v[i] - mean) * rs * wv8[i] + bv8[i]);
  *(uint4*)(outp + row * D_ + lane * 8) = o.v;
}

// =====================================================================
// Merged prep: all 4 weight transposes (fp32 KxN -> bf16 NxK), fsmn
// reorder (o,i,tap)->(o, tap*512+i), and vmpad pad-row zeroing.
// grid: [0,768) qkv_w | [768,1024) out_w | [1024,2048) w1 | [2048,3072) w2
//       [3072,4096) fsmn reorder | [4096,4256) vmpad pad rows
// =====================================================================
__global__ __launch_bounds__(256)
void prep_all(const float* __restrict__ qkv_w, const float* __restrict__ out_w,
              const float* __restrict__ w1, const float* __restrict__ w2,
              const float* __restrict__ fsmn_w,
              u16* __restrict__ qkv_wT, u16* __restrict__ out_wT,
              u16* __restrict__ w1T, u16* __restrict__ w2T,
              u16* __restrict__ fsmnW2, u16* __restrict__ vmpad)
{
  const int bid = blockIdx.x;
  if (bid < 3072) {
    const float* src; u16* dst; int K, N, tb;
    if (bid < 768)       { src = qkv_w; dst = qkv_wT; K = 512;  N = 1536; tb = bid; }
    else if (bid < 1024) { src = out_w; dst = out_wT; K = 512;  N = 512;  tb = bid - 768; }
    else if (bid < 2048) { src = w1;    dst = w1T;    K = 512;  N = 2048; tb = bid - 1024; }
    else                 { src = w2;    dst = w2T;    K = 2048; N = 512;  tb = bid - 2048; }
    const int ktiles = K / 32;
    const int k0 = (tb % ktiles) * 32, n0 = (tb / ktiles) * 32;
    __shared__ float tile[32][33];
    const int x = threadIdx.x & 31, y = threadIdx.x >> 5;
#pragma unroll
    for (int j = 0; j < 4; j++)
      tile[y + j * 8][x] = src[(size_t)(k0 + y + j * 8) * N + n0 + x];
    __syncthreads();
#pragma unroll
    for (int j = 0; j < 4; j++)
      dst[(size_t)(n0 + y + j * 8) * K + k0 + x] = f2b(tile[x][y + j * 8]);
  } else if (bid < 4096) {
    const int idx = (bid - 3072) * 256 + threadIdx.x;   // o*512+i
    const int o = idx >> 9, i = idx & 511;
    const float* s = fsmn_w + (size_t)idx * 11;
#pragma unroll
    for (int tap = 0; tap < 11; ++tap)
      fsmnW2[(size_t)o * KC_ + tap * 512 + i] = f2b(s[tap]);
  } else {
    // zero the 10 pad rows per batch (rows 0..4 and 223..227 of each 228-row slab)
    const int e8 = (bid - 4096) * 256 + threadIdx.x;  // uint4 index, < 40960
    const int e  = e8 * 8;
    const int c  = e & 511;
    const int pr = e >> 9;              // 0..639
    const int b  = pr / 10, j = pr % 10;
    const int row = (j < 5) ? j : (218 + j);   // 0..4 or 223..227
    *(uint4*)(vmpad + ((size_t)b * TP_ + row) * D_ + c) = make_uint4(0, 0, 0, 0);
  }
}

// Vt[bh][d][kv] = v[b, kv, h*128+d]  grid (7 kv-tiles, 4 d-tiles, 256 bh)
__global__ void fill_vt(const u16* __restrict__ qkv, u16* __restrict__ Vt)
{
  __shared__ u16 tile[32][33];
  const int bh = blockIdx.z, b = bh >> 2, h = bh & 3;
  const int kv0 = blockIdx.x * 32, d0 = blockIdx.y * 32;
  const int x = threadIdx.x & 31, y = threadIdx.x >> 5;
#pragma unroll
  for (int j = 0; j < 4; j++) {
    const int kv = kv0 + y + j * 8;
    u16 v = 0;
    if (kv < T_) v = qkv[((size_t)b * T_ + kv) * N3_ + 1024 + h * DK_ + d0 + x];
    tile[y + j * 8][x] = v;
  }
  __syncthreads();
#pragma unroll
  for (int j = 0; j < 4; j++) {
    const int d = d0 + y + j * 8;
    Vt[((size_t)bh * 128 + d) * PW_ + kv0 + x] = tile[x][y + j * 8];
  }
}

// =====================================================================
extern "C" void kernel_launch(void* const* d_in, const int* in_sizes, int n_in,
                              void* d_out, int out_size, void* d_ws, size_t ws_size,
                              hipStream_t stream)
{
  const float* x      = (const float*)d_in[0];
  const float* masks  = (const float*)d_in[1];
  const float* ln0_w  = (const float*)d_in[2];
  const float* ln0_b  = (const float*)d_in[3];
  const float* ln1_w  = (const float*)d_in[4];
  const float* ln1_b  = (const float*)d_in[5];
  const float* qkv_w  = (const float*)d_in[6];
  const float* qkv_b  = (const float*)d_in[7];
  const float* out_w  = (const float*)d_in[8];
  const float* out_b  = (const float*)d_in[9];
  const float* fsmn_w = (const float*)d_in[10];
  const float* w1     = (const float*)d_in[11];
  const float* b1     = (const float*)d_in[12];
  const float* w2     = (const float*)d_in[13];
  const float* b2     = (const float*)d_in[14];
  float* outp = (float*)d_out;
  u16* ws   = (u16*)d_ws;

  size_t off = 0;
  u16* qkv_wT = ws + off; off += (size_t)1536 * 512;
  u16* out_wT = ws + off; off += (size_t)512 * 512;
  u16* w1T    = ws + off; off += (size_t)2048 * 512;
  u16* w2T    = ws + off; off += (size_t)512 * 2048;
  u16* fsmnW2 = ws + off; off += (size_t)512 * KC_;       // (512o, 5632k)
  u16* slotA  = ws + off; off += (size_t)M_ * 512;        // h (ln0) -> ctx
  u16* qkvb   = ws + off; off += (size_t)M_ * 1536;       // qkv; later h1 + x1
  u16* vmpad  = ws + off; off += (size_t)B_ * TP_ * 512;  // padded v*mask
  u16* regionX= ws + off;
  // regionX: Pbuf (14.68M u16) + Vtbuf (7.34M) + convacc (2*M*512 f32).
  // hid (M*2048 u16) aliases regionX front after attention+conv consumed.
  u16* Pbuf   = regionX;                                   // 256*256*224
  u16* Vtbuf  = regionX + (size_t)256 * 256 * PW_;         // 256*128*224
  float* convacc = (float*)(Vtbuf + (size_t)256 * 128 * PW_); // 2 * M*512 fp32
  u16* hid    = regionX;                                   // M*2048 bf16
  u16* h1     = qkvb;                                      // M*512 bf16
  float* x1   = (float*)(qkvb + (size_t)M_ * 512);         // M*512 fp32

  // weight prep + vmpad pad-row zeroing, one launch
  prep_all<<<4256, 256, 0, stream>>>(qkv_w, out_w, w1, w2, fsmn_w,
                                     qkv_wT, out_wT, w1T, w2T, fsmnW2, vmpad);
  // ln0 -> h
  ln_k<<<M_ / 4, 256, 0, stream>>>(x, ln0_w, ln0_b, slotA);
  // qkv = h @ qkv_w + b  (bf16 out; v-cols also populate vmpad interior)
  // swizzled 1D grid: 8 * ceil(109/8) * ntc
  gemm_u<0><<<8 * 14 * 12, 256, 0, stream>>>(
      slotA, 512, qkv_wT, 512, qkv_b, nullptr, nullptr, vmpad, nullptr, qkvb,
      1536, 512, 12, masks);
  // fsmn conv: strided im2col GEMM, split-K x2; XCD owns (n,z), m streams
  gemm_u<4><<<MT_ * 8, 256, 0, stream>>>(
      vmpad, 0, fsmnW2, KC_, nullptr, nullptr, nullptr, nullptr, nullptr, convacc,
      512, KH_, 4, nullptr);
  // attention
  fill_vt<<<dim3(7, 4, 256), 256, 0, stream>>>(qkvb, Vtbuf);
  attn_scores<<<dim3(4, 256), 256, 0, stream>>>(qkvb, masks, Pbuf);
  gemm_u<5><<<dim3(2, 1, 256), 256, 0, stream>>>(
      Pbuf, PW_, Vtbuf, PW_, nullptr, nullptr, nullptr, nullptr, nullptr, slotA,
      128, PW_, 1, nullptr);
  // x1 = x + ctx@out_w + out_b + (conv0+conv1+vm)*mask   (fp32 out)
  gemm_u<1><<<8 * 14 * 4, 256, 0, stream>>>(
      slotA, 512, out_wT, 512, out_b, convacc, vmpad, nullptr, x, x1,
      512, 512, 4, masks);
  // ffn
  ln_k<<<M_ / 4, 256, 0, stream>>>(x1, ln1_w, ln1_b, h1);
  gemm_u<2><<<8 * 14 * 16, 256, 0, stream>>>(
      h1, 512, w1T, 512, b1, nullptr, nullptr, nullptr, nullptr, hid,
      2048, 512, 16, nullptr);
  gemm_u<3><<<8 * 14 * 4, 256, 0, stream>>>(
      hid, 2048, w2T, 2048, b2, nullptr, nullptr, nullptr, x1, outp,
      512, 2048, 4, nullptr);
}

// Round 7
// 504.879 us; speedup vs baseline: 1.1802x; 1.0139x over previous
//
#include <hip/hip_runtime.h>
#include <cstdint>

// ---- problem constants ----
#define B_   64
#define T_   218
#define TP_  228          // T + 2*PAD
#define D_   512
#define M_   13952        // B_*T_  (= 109*128, exact)
#define MT_  109          // m-tiles
#define H_   4
#define DK_  128
#define PW_  224          // padded KV width for attention (7*32)
#define N3_  1536
#define DFF_ 2048
#define KC_  5632         // conv im2col K = 11*512
#define KH_  2816         // conv split-K half

typedef unsigned short u16;   // raw bf16
using short8 = __attribute__((ext_vector_type(8))) short;
using f32x4  = __attribute__((ext_vector_type(4))) float;

__device__ __forceinline__ float b2f(u16 u) {
  union { float f; uint32_t i; } v; v.i = ((uint32_t)u) << 16; return v.f;
}
__device__ __forceinline__ u16 f2b(float f) {
  union { float f; uint32_t i; } v; v.f = f;
  uint32_t r = v.i + 0x7fffu + ((v.i >> 16) & 1u);
  return (u16)(r >> 16);
}
union U8 { uint4 v; u16 u[8]; };

// async global->LDS, 16 bytes per lane; LDS dest is wave-uniform base + lane*16
__device__ __forceinline__ void gll16(const u16* g, u16* l) {
  __builtin_amdgcn_global_load_lds(
      (const __attribute__((address_space(1))) unsigned int*)g,
      (__attribute__((address_space(3))) unsigned int*)l, 16, 0, 0);
}

// =====================================================================
// Unified 128x128 MFMA GEMM with global_load_lds staging (m97 structure)
// and XCD-aware 1D block swizzle (blockIdx%8 -> XCD heuristic).
// out[M,N] = A[M,K] (row stride sA) @ Bt[N,K]^T (row stride sB), + epilogue.
// MODE 0: bf16 out = acc+bias; v-cols also write vmpad (qkv)
// MODE 1: f32  out = acc+bias+(conv0+conv1+vm)*m+add_f (out-proj +fsmn +x)
// MODE 2: bf16 out = relu(acc+bias)                   (ffn1)
// MODE 3: f32  out = acc+bias+add_f                   (ffn2 +x1 -> d_out)
// MODE 4: conv im2col split-K: XCD owns (n,z); bf16 store to half z
// =====================================================================
template<int MODE>
__global__ __launch_bounds__(256, 2)
void gemm_u(const u16* __restrict__ A, int sA, const u16* __restrict__ Bt, int sB,
            const float* __restrict__ bias, const u16* __restrict__ convb,
            const u16* __restrict__ vmp, u16* __restrict__ vmout,
            const float* __restrict__ add_f, void* __restrict__ outp,
            int N, int K, int ntc, const float* __restrict__ masks)
{
  __shared__ u16 As[128 * 32];
  __shared__ u16 Bs[128 * 32];

  // ---- block decode (1D swizzled) ----
  int mt, nt, zb = 0;
  if (MODE == 4) {
    const int j = blockIdx.x & 7;      // (n,z) combo -> XCD j
    nt = j & 3; zb = j >> 2;
    mt = blockIdx.x >> 3;              // m streams within XCD
  } else {
    const int xcd = blockIdx.x & 7;
    const int lin = blockIdx.x >> 3;
    nt = lin % ntc;                    // n fastest: A-tile reuse in L2
    mt = xcd + 8 * (lin / ntc);        // m%8 == xcd: B pinned per XCD
    if (mt >= MT_) return;
  }
  const int m0 = mt * 128, n0 = nt * 128;

  const int tid = threadIdx.x, lane = tid & 63, w = tid >> 6;
  const int wm = (w >> 1) * 64, wn = (w & 1) * 64;
  const int l15 = lane & 15, qd = lane >> 4;

  // staging: wave w, issue j in {0,1}; lane covers row = j*64 + w*16 + lane/4,
  // 16B chunk = lane%4 of the 128x32 tile.
  const int rl = lane >> 2, ce = (lane & 3) * 8;
  const int r0 = m0 + w * 16 + rl, r1 = r0 + 64;
  size_t aoff0, aoff1, bkoff = 0;
  if (MODE == 4) {
    const int b0r = r0 / T_, t0r = r0 - b0r * T_;
    const int b1r = r1 / T_, t1r = r1 - b1r * T_;
    aoff0 = ((size_t)b0r * TP_ + t0r) * D_ + (size_t)zb * KH_;
    aoff1 = ((size_t)b1r * TP_ + t1r) * D_ + (size_t)zb * KH_;
    bkoff = (size_t)zb * KH_;
  } else {
    aoff0 = (size_t)r0 * sA;
    aoff1 = (size_t)r1 * sA;
  }
  const u16* ag0 = A + aoff0 + ce;
  const u16* ag1 = A + aoff1 + ce;
  const u16* bg0 = Bt + (size_t)(n0 + w * 16 + rl) * sB + bkoff + ce;
  const u16* bg1 = bg0 + (size_t)64 * sB;
  u16* lA0 = As + w * 512;
  u16* lA1 = As + 2048 + w * 512;
  u16* lB0 = Bs + w * 512;
  u16* lB1 = Bs + 2048 + w * 512;

  const f32x4 z4 = {0.f, 0.f, 0.f, 0.f};
  f32x4 acc[4][4];
#pragma unroll
  for (int i = 0; i < 4; i++)
#pragma unroll
    for (int j = 0; j < 4; j++) acc[i][j] = z4;

  for (int k0 = 0; k0 < K; k0 += 32) {
    __syncthreads();
    gll16(ag0 + k0, lA0);
    gll16(ag1 + k0, lA1);
    gll16(bg0 + k0, lB0);
    gll16(bg1 + k0, lB1);
    __syncthreads();
    short8 af[4], bf[4];
#pragma unroll
    for (int mi = 0; mi < 4; mi++) af[mi] = *(const short8*)&As[(wm + mi * 16 + l15) * 32 + qd * 8];
#pragma unroll
    for (int ni = 0; ni < 4; ni++) bf[ni] = *(const short8*)&Bs[(wn + ni * 16 + l15) * 32 + qd * 8];
#pragma unroll
    for (int mi = 0; mi < 4; mi++)
#pragma unroll
      for (int ni = 0; ni < 4; ni++)
        acc[mi][ni] = __builtin_amdgcn_mfma_f32_16x16x32_bf16(af[mi], bf[ni], acc[mi][ni], 0, 0, 0);
  }

#pragma unroll
  for (int ni = 0; ni < 4; ni++) {
    const int c = n0 + wn + ni * 16 + l15;
    const float bv = (MODE == 4) ? 0.f : bias[c];
#pragma unroll
    for (int mi = 0; mi < 4; mi++) {
#pragma unroll
      for (int rg = 0; rg < 4; rg++) {
        const int r = m0 + wm + mi * 16 + qd * 4 + rg;
        float v = acc[mi][ni][rg] + bv;
        if (MODE == 0) {
          ((u16*)outp)[(size_t)r * N + c] = f2b(v);
          if (c >= 1024) {   // v columns: also write masked-v into padded conv input
            const int b = r / T_, t = r - b * T_;
            vmout[((size_t)b * TP_ + t + 5) * D_ + (c - 1024)] = f2b(v * masks[r]);
          }
        } else if (MODE == 1) {
          const size_t idx = (size_t)r * N + c;
          const int b = r / T_, t = r - b * T_;
          const float m  = masks[r];
          const float cv = b2f(convb[idx]) + b2f(convb[idx + (size_t)M_ * 512]);
          const float vm = b2f(vmp[((size_t)b * TP_ + t + 5) * D_ + c]);
          ((float*)outp)[idx] = v + (cv + vm) * m + add_f[idx];
        } else if (MODE == 2) {
          ((u16*)outp)[(size_t)r * N + c] = f2b(fmaxf(v, 0.f));
        } else if (MODE == 3) {
          const size_t idx = (size_t)r * N + c;
          ((float*)outp)[idx] = v + add_f[idx];
        } else {  // MODE 4: bf16 partial store for half zb
          ((u16*)outp)[(size_t)zb * ((size_t)M_ * 512) + (size_t)r * N + c] = f2b(v);
        }
      }
    }
  }
}

// =====================================================================
// Fused attention: per (q-tile of 64, bh) block computes
// P = softmax(mask(QK^T/sqrt(dk))) entirely in LDS, then ctx = P@V.
// P round-trips C-layout -> LDS -> A-frag layout (m120-verified pattern).
// V transposed into LDS per 64-d half. LDS: phase1 Qs/Ks (34 KB) aliased
// with phase2 Ps/Vs (58 KB); 60 KB static -> 2 blocks/CU.
// =====================================================================
__global__ __launch_bounds__(256, 2)
void attn_fused(const u16* __restrict__ qkv, const float* __restrict__ masks,
                u16* __restrict__ ctx)
{
  __shared__ u16 smem[29696];        // 59392 B
  __shared__ float red0[4][64];
  __shared__ float red1[4][64];
  u16* Qs = smem;                    // [64][136] phase 1
  u16* Ks = smem + 64 * 136;         // [64][136]
  u16* Ps = smem;                    // [64][232] phase 2 (aliases Qs)
  u16* Vs = smem + 64 * 232;         // [64][232] (aliases Ks tail)

  const int tid = threadIdx.x, lane = tid & 63, w = tid >> 6;
  const int l15 = lane & 15, qd = lane >> 4;
  const int bh = blockIdx.y, b = bh >> 2, h = bh & 3;
  const int q0 = blockIdx.x * 64;
  const uint4 uz = make_uint4(0, 0, 0, 0);

  // stage Q (64 rows x 128)
#pragma unroll
  for (int i = 0; i < 4; i++) {
    const int ch = tid + i * 256;
    const int row = ch >> 4, cg = (ch & 15) * 8;
    const int t = q0 + row;
    uint4 v = uz;
    if (t < T_) v = *(const uint4*)(qkv + ((size_t)b * T_ + t) * N3_ + h * DK_ + cg);
    *(uint4*)&Qs[row * 136 + cg] = v;
  }

  const f32x4 z4 = {0.f, 0.f, 0.f, 0.f};
  f32x4 acc[4][4];   // [kv-chunk][q-subtile]
#pragma unroll
  for (int i = 0; i < 4; i++)
#pragma unroll
    for (int j = 0; j < 4; j++) acc[i][j] = z4;

#pragma unroll
  for (int kc = 0; kc < 4; kc++) {
    __syncthreads();
#pragma unroll
    for (int i = 0; i < 4; i++) {
      const int ch = tid + i * 256;
      const int row = ch >> 4, cg = (ch & 15) * 8;
      const int t = kc * 64 + row;
      uint4 v = uz;
      if (t < T_) v = *(const uint4*)(qkv + ((size_t)b * T_ + t) * N3_ + D_ + h * DK_ + cg);
      *(uint4*)&Ks[row * 136 + cg] = v;
    }
    __syncthreads();
#pragma unroll
    for (int ks = 0; ks < 4; ks++) {
      short8 bf = *(const short8*)&Ks[(w * 16 + l15) * 136 + ks * 32 + qd * 8];
#pragma unroll
      for (int mi = 0; mi < 4; mi++) {
        short8 af = *(const short8*)&Qs[(mi * 16 + l15) * 136 + ks * 32 + qd * 8];
        acc[kc][mi] = __builtin_amdgcn_mfma_f32_16x16x32_bf16(af, bf, acc[kc][mi], 0, 0, 0);
      }
    }
  }

  const float scale = 0.08838834764831845f;  // 1/sqrt(128)
  const int colb = w * 16 + l15;
  bool valid[4];
#pragma unroll
  for (int kc = 0; kc < 4; kc++) {
    const int col = kc * 64 + colb;
    valid[kc] = (col < T_) && (masks[b * T_ + col] > 0.f);
  }

  float mx[4][4];
#pragma unroll
  for (int mi = 0; mi < 4; mi++)
#pragma unroll
    for (int rg = 0; rg < 4; rg++) {
      float m = -1e30f;
#pragma unroll
      for (int kc = 0; kc < 4; kc++)
        if (valid[kc]) m = fmaxf(m, acc[kc][mi][rg] * scale);
      for (int d = 1; d < 16; d <<= 1) m = fmaxf(m, __shfl_xor(m, d, 64));
      mx[mi][rg] = m;
    }
  if (l15 == 0) {
#pragma unroll
    for (int mi = 0; mi < 4; mi++)
#pragma unroll
      for (int rg = 0; rg < 4; rg++) red0[w][mi * 16 + qd * 4 + rg] = mx[mi][rg];
  }
  __syncthreads();
#pragma unroll
  for (int mi = 0; mi < 4; mi++)
#pragma unroll
    for (int rg = 0; rg < 4; rg++) {
      const int r = mi * 16 + qd * 4 + rg;
      mx[mi][rg] = fmaxf(fmaxf(red0[0][r], red0[1][r]), fmaxf(red0[2][r], red0[3][r]));
    }
  float sm[4][4];
#pragma unroll
  for (int mi = 0; mi < 4; mi++)
#pragma unroll
    for (int rg = 0; rg < 4; rg++) {
      float s = 0.f;
#pragma unroll
      for (int kc = 0; kc < 4; kc++)
        if (valid[kc]) s += __expf(acc[kc][mi][rg] * scale - mx[mi][rg]);
      for (int d = 1; d < 16; d <<= 1) s += __shfl_xor(s, d, 64);
      sm[mi][rg] = s;
    }
  if (l15 == 0) {
#pragma unroll
    for (int mi = 0; mi < 4; mi++)
#pragma unroll
      for (int rg = 0; rg < 4; rg++) red1[w][mi * 16 + qd * 4 + rg] = sm[mi][rg];
  }
  __syncthreads();
  // all Qs/Ks reads complete (last sync) -> safe to overwrite with Ps
#pragma unroll
  for (int mi = 0; mi < 4; mi++)
#pragma unroll
    for (int rg = 0; rg < 4; rg++) {
      const int r = mi * 16 + qd * 4 + rg;
      const float inv = 1.f / (red1[0][r] + red1[1][r] + red1[2][r] + red1[3][r]);
#pragma unroll
      for (int kc = 0; kc < 4; kc++) {
        const int col = kc * 64 + colb;
        if (col < PW_) {
          const float p = valid[kc] ? __expf(acc[kc][mi][rg] * scale - mx[mi][rg]) * inv : 0.f;
          Ps[r * 232 + col] = f2b(p);
        }
      }
    }

  // ---- phase 2: ctx = P @ V, per 64-d half ----
  const int kvg = tid >> 4, dg = tid & 15;
#pragma unroll
  for (int half = 0; half < 2; ++half) {
    __syncthreads();  // Ps visible / previous PV reads of Vs done
    // stage V^T: Vs[d'][kv], d' = dg*4+j (within half), kv = r*16+kvg
#pragma unroll
    for (int r = 0; r < 14; ++r) {
      const int kv = r * 16 + kvg;
      ushort4 vv = make_ushort4(0, 0, 0, 0);
      if (kv < T_)
        vv = *(const ushort4*)(qkv + ((size_t)b * T_ + kv) * N3_ + 1024 + h * DK_ + half * 64 + dg * 4);
      Vs[(dg * 4 + 0) * 232 + kv] = vv.x;
      Vs[(dg * 4 + 1) * 232 + kv] = vv.y;
      Vs[(dg * 4 + 2) * 232 + kv] = vv.z;
      Vs[(dg * 4 + 3) * 232 + kv] = vv.w;
    }
    __syncthreads();
    f32x4 a2[4] = {z4, z4, z4, z4};
#pragma unroll
    for (int k0 = 0; k0 < 7; ++k0) {
      short8 af = *(const short8*)&Ps[(w * 16 + l15) * 232 + k0 * 32 + qd * 8];
#pragma unroll
      for (int nt = 0; nt < 4; ++nt) {
        short8 bf = *(const short8*)&Vs[(nt * 16 + l15) * 232 + k0 * 32 + qd * 8];
        a2[nt] = __builtin_amdgcn_mfma_f32_16x16x32_bf16(af, bf, a2[nt], 0, 0, 0);
      }
    }
    const int tb = q0 + w * 16 + qd * 4;
#pragma unroll
    for (int nt = 0; nt < 4; ++nt) {
      const int d = h * DK_ + half * 64 + nt * 16 + l15;
#pragma unroll
      for (int rg = 0; rg < 4; ++rg) {
        const int tt = tb + rg;
        if (tt < T_) ctx[((size_t)b * T_ + tt) * D_ + d] = f2b(a2[nt][rg]);
      }
    }
  }
}

// ======================= small support kernels =======================
// LayerNorm: fp32 in -> bf16 out. 4 rows/block (one per wave).
__global__ __launch_bounds__(256)
void ln_k(const float* __restrict__ x, const float* __restrict__ wgt,
          const float* __restrict__ bia, u16* __restrict__ outp)
{
  const int lane = threadIdx.x & 63, wv = threadIdx.x >> 6;
  const size_t row = (size_t)blockIdx.x * 4 + wv;
  const float* rp = x + row * D_ + lane * 8;
  float v[8], s = 0.f, s2 = 0.f;
  float4 r0 = *(const float4*)rp;
  float4 r1 = *(const float4*)(rp + 4);
  v[0] = r0.x; v[1] = r0.y; v[2] = r0.z; v[3] = r0.w;
  v[4] = r1.x; v[5] = r1.y; v[6] = r1.z; v[7] = r1.w;
#pragma unroll
  for (int i = 0; i < 8; i++) { s += v[i]; s2 += v[i] * v[i]; }
  for (int d = 1; d < 64; d <<= 1) { s += __shfl_xor(s, d, 64); s2 += __shfl_xor(s2, d, 64); }
  const float mean = s * (1.f / 512.f);
  const float var  = s2 * (1.f / 512.f) - mean * mean;
  const float rs   = rsqrtf(var + 1e-5f);
  float4 w0 = *(const float4*)(wgt + lane * 8);
  float4 w1 = *(const float4*)(wgt + lane * 8 + 4);
  float4 b0 = *(const float4*)(bia + lane * 8);
  float4 b1 = *(const float4*)(bia + lane * 8 + 4);
  const float wv8[8] = {w0.x, w0.y, w0.z, w0.w, w1.x, w1.y, w1.z, w1.w};
  const float bv8[8] = {b0.x, b0.y, b0.z, b0.w, b1.x, b1.y, b1.z, b1.w};
  U8 o;
#pragma unroll
  for (int i = 0; i < 8; i++)
    o.u[i] = f2b((v[i] - mean) * rs * wv8[i] + bv8[i]);
  *(uint4*)(outp + row * D_ + lane * 8) = o.v;
}

// =====================================================================
// Merged prep: all 4 weight transposes (fp32 KxN -> bf16 NxK), fsmn
// reorder (o,i,tap)->(o, tap*512+i), and vmpad pad-row zeroing.
// =====================================================================
__global__ __launch_bounds__(256)
void prep_all(const float* __restrict__ qkv_w, const float* __restrict__ out_w,
              const float* __restrict__ w1, const float* __restrict__ w2,
              const float* __restrict__ fsmn_w,
              u16* __restrict__ qkv_wT, u16* __restrict__ out_wT,
              u16* __restrict__ w1T, u16* __restrict__ w2T,
              u16* __restrict__ fsmnW2, u16* __restrict__ vmpad)
{
  const int bid = blockIdx.x;
  if (bid < 3072) {
    const float* src; u16* dst; int K, N, tb;
    if (bid < 768)       { src = qkv_w; dst = qkv_wT; K = 512;  N = 1536; tb = bid; }
    else if (bid < 1024) { src = out_w; dst = out_wT; K = 512;  N = 512;  tb = bid - 768; }
    else if (bid < 2048) { src = w1;    dst = w1T;    K = 512;  N = 2048; tb = bid - 1024; }
    else                 { src = w2;    dst = w2T;    K = 2048; N = 512;  tb = bid - 2048; }
    const int ktiles = K / 32;
    const int k0 = (tb % ktiles) * 32, n0 = (tb / ktiles) * 32;
    __shared__ float tile[32][33];
    const int x = threadIdx.x & 31, y = threadIdx.x >> 5;
#pragma unroll
    for (int j = 0; j < 4; j++)
      tile[y + j * 8][x] = src[(size_t)(k0 + y + j * 8) * N + n0 + x];
    __syncthreads();
#pragma unroll
    for (int j = 0; j < 4; j++)
      dst[(size_t)(n0 + y + j * 8) * K + k0 + x] = f2b(tile[x][y + j * 8]);
  } else if (bid < 4096) {
    const int idx = (bid - 3072) * 256 + threadIdx.x;   // o*512+i
    const int o = idx >> 9, i = idx & 511;
    const float* s = fsmn_w + (size_t)idx * 11;
#pragma unroll
    for (int tap = 0; tap < 11; ++tap)
      fsmnW2[(size_t)o * KC_ + tap * 512 + i] = f2b(s[tap]);
  } else {
    // zero the 10 pad rows per batch (rows 0..4 and 223..227 of each 228-row slab)
    const int e8 = (bid - 4096) * 256 + threadIdx.x;  // uint4 index, < 40960
    const int e  = e8 * 8;
    const int c  = e & 511;
    const int pr = e >> 9;              // 0..639
    const int b  = pr / 10, j = pr % 10;
    const int row = (j < 5) ? j : (218 + j);   // 0..4 or 223..227
    *(uint4*)(vmpad + ((size_t)b * TP_ + row) * D_ + c) = make_uint4(0, 0, 0, 0);
  }
}

// =====================================================================
extern "C" void kernel_launch(void* const* d_in, const int* in_sizes, int n_in,
                              void* d_out, int out_size, void* d_ws, size_t ws_size,
                              hipStream_t stream)
{
  const float* x      = (const float*)d_in[0];
  const float* masks  = (const float*)d_in[1];
  const float* ln0_w  = (const float*)d_in[2];
  const float* ln0_b  = (const float*)d_in[3];
  const float* ln1_w  = (const float*)d_in[4];
  const float* ln1_b  = (const float*)d_in[5];
  const float* qkv_w  = (const float*)d_in[6];
  const float* qkv_b  = (const float*)d_in[7];
  const float* out_w  = (const float*)d_in[8];
  const float* out_b  = (const float*)d_in[9];
  const float* fsmn_w = (const float*)d_in[10];
  const float* w1     = (const float*)d_in[11];
  const float* b1     = (const float*)d_in[12];
  const float* w2     = (const float*)d_in[13];
  const float* b2     = (const float*)d_in[14];
  float* outp = (float*)d_out;
  u16* ws   = (u16*)d_ws;

  size_t off = 0;
  u16* qkv_wT = ws + off; off += (size_t)1536 * 512;
  u16* out_wT = ws + off; off += (size_t)512 * 512;
  u16* w1T    = ws + off; off += (size_t)2048 * 512;
  u16* w2T    = ws + off; off += (size_t)512 * 2048;
  u16* fsmnW2 = ws + off; off += (size_t)512 * KC_;       // (512o, 5632k)
  u16* slotA  = ws + off; off += (size_t)M_ * 512;        // h (ln0) -> ctx
  u16* qkvb   = ws + off; off += (size_t)M_ * 1536;       // qkv; later h1 + x1
  u16* vmpad  = ws + off; off += (size_t)B_ * TP_ * 512;  // padded v*mask
  u16* regionX= ws + off;
  // regionX: convacc (2 * M*512 bf16) dead after out-proj; hid (M*2048 bf16)
  // live from ffn1 -> both alias regionX.
  u16* convacc = regionX;                                  // 2 * M*512 bf16
  u16* hid     = regionX;                                  // M*2048 bf16
  u16* h1      = qkvb;                                     // M*512 bf16
  float* x1    = (float*)(qkvb + (size_t)M_ * 512);        // M*512 fp32

  // weight prep + vmpad pad-row zeroing, one launch
  prep_all<<<4256, 256, 0, stream>>>(qkv_w, out_w, w1, w2, fsmn_w,
                                     qkv_wT, out_wT, w1T, w2T, fsmnW2, vmpad);
  // ln0 -> h
  ln_k<<<M_ / 4, 256, 0, stream>>>(x, ln0_w, ln0_b, slotA);
  // qkv = h @ qkv_w + b  (bf16 out; v-cols also populate vmpad interior)
  gemm_u<0><<<8 * 14 * 12, 256, 0, stream>>>(
      slotA, 512, qkv_wT, 512, qkv_b, nullptr, nullptr, vmpad, nullptr, qkvb,
      1536, 512, 12, masks);
  // fsmn conv: strided im2col GEMM, split-K x2; XCD owns (n,z); bf16 partials
  gemm_u<4><<<MT_ * 8, 256, 0, stream>>>(
      vmpad, 0, fsmnW2, KC_, nullptr, nullptr, nullptr, nullptr, nullptr, convacc,
      512, KH_, 4, nullptr);
  // fused attention -> ctx in slotA
  attn_fused<<<dim3(4, 256), 256, 0, stream>>>(qkvb, masks, slotA);
  // x1 = x + ctx@out_w + out_b + (conv0+conv1+vm)*mask   (fp32 out)
  gemm_u<1><<<8 * 14 * 4, 256, 0, stream>>>(
      slotA, 512, out_wT, 512, out_b, convacc, vmpad, nullptr, x, x1,
      512, 512, 4, masks);
  // ffn
  ln_k<<<M_ / 4, 256, 0, stream>>>(x1, ln1_w, ln1_b, h1);
  gemm_u<2><<<8 * 14 * 16, 256, 0, stream>>>(
      h1, 512, w1T, 512, b1, nullptr, nullptr, nullptr, nullptr, hid,
      2048, 512, 16, nullptr);
  gemm_u<3><<<8 * 14 * 4, 256, 0, stream>>>(
      hid, 2048, w2T, 2048, b2, nullptr, nullptr, nullptr, x1, outp,
      512, 2048, 4, nullptr);
}

// Round 8
// 452.981 us; speedup vs baseline: 1.3154x; 1.1146x over previous
//
#include <hip/hip_runtime.h>
#include <cstdint>

// ---- problem constants ----
#define B_   64
#define T_   218
#define TP_  228          // T + 2*PAD
#define D_   512
#define M_   13952        // B_*T_  (= 109*128, exact)
#define MT_  109          // m-tiles (128)
#define H_   4
#define DK_  128
#define N3_  1536
#define DFF_ 2048
#define KC_  5632         // conv im2col K = 11*512

typedef unsigned short u16;   // raw bf16
using short8 = __attribute__((ext_vector_type(8))) short;
using f32x4  = __attribute__((ext_vector_type(4))) float;

__device__ __forceinline__ float b2f(u16 u) {
  union { float f; uint32_t i; } v; v.i = ((uint32_t)u) << 16; return v.f;
}
__device__ __forceinline__ u16 f2b(float f) {
  union { float f; uint32_t i; } v; v.f = f;
  uint32_t r = v.i + 0x7fffu + ((v.i >> 16) & 1u);
  return (u16)(r >> 16);
}
union U8 { uint4 v; u16 u[8]; };

// async global->LDS, 16 bytes per lane; LDS dest is wave-uniform base + lane*16
__device__ __forceinline__ void gll16(const u16* g, u16* l) {
  __builtin_amdgcn_global_load_lds(
      (const __attribute__((address_space(1))) unsigned int*)g,
      (__attribute__((address_space(3))) unsigned int*)l, 16, 0, 0);
}

// =====================================================================
// Unified 128x128 MFMA GEMM with global_load_lds staging (m97 structure)
// and XCD-aware 1D block swizzle (blockIdx%8 -> XCD heuristic).
// out[M,N] = A[M,K] (row stride sA) @ Bt[N,K]^T (row stride sB), + epilogue.
// MODE 0: bf16 out = acc+bias; v-cols also write vmpad (qkv)
// MODE 1: f32  out = acc+bias+convb+add_f             (out-proj +fsmn +x)
// MODE 2: bf16 out = relu(acc+bias)                   (ffn1)
// MODE 3: f32  out = acc+bias+add_f                   (ffn2 +x1 -> d_out)
// =====================================================================
template<int MODE>
__global__ __launch_bounds__(256, 2)
void gemm_u(const u16* __restrict__ A, int sA, const u16* __restrict__ Bt, int sB,
            const float* __restrict__ bias, const u16* __restrict__ convb,
            u16* __restrict__ vmout,
            const float* __restrict__ add_f, void* __restrict__ outp,
            int N, int K, int ntc, const float* __restrict__ masks)
{
  __shared__ u16 As[128 * 32];
  __shared__ u16 Bs[128 * 32];

  // ---- block decode: weight-stationary XCD swizzle ----
  const int xcd = blockIdx.x & 7;
  const int lin = blockIdx.x >> 3;
  const int nt = lin % ntc;            // n fastest: A-tile reuse in L2
  const int mt = xcd + 8 * (lin / ntc);// m%8 == xcd
  if (mt >= MT_) return;
  const int m0 = mt * 128, n0 = nt * 128;

  const int tid = threadIdx.x, lane = tid & 63, w = tid >> 6;
  const int wm = (w >> 1) * 64, wn = (w & 1) * 64;
  const int l15 = lane & 15, qd = lane >> 4;

  const int rl = lane >> 2, ce = (lane & 3) * 8;
  const int r0 = m0 + w * 16 + rl, r1 = r0 + 64;
  const u16* ag0 = A + (size_t)r0 * sA + ce;
  const u16* ag1 = A + (size_t)r1 * sA + ce;
  const u16* bg0 = Bt + (size_t)(n0 + w * 16 + rl) * sB + ce;
  const u16* bg1 = bg0 + (size_t)64 * sB;
  u16* lA0 = As + w * 512;
  u16* lA1 = As + 2048 + w * 512;
  u16* lB0 = Bs + w * 512;
  u16* lB1 = Bs + 2048 + w * 512;

  const f32x4 z4 = {0.f, 0.f, 0.f, 0.f};
  f32x4 acc[4][4];
#pragma unroll
  for (int i = 0; i < 4; i++)
#pragma unroll
    for (int j = 0; j < 4; j++) acc[i][j] = z4;

  for (int k0 = 0; k0 < K; k0 += 32) {
    __syncthreads();
    gll16(ag0 + k0, lA0);
    gll16(ag1 + k0, lA1);
    gll16(bg0 + k0, lB0);
    gll16(bg1 + k0, lB1);
    __syncthreads();
    short8 af[4], bf[4];
#pragma unroll
    for (int mi = 0; mi < 4; mi++) af[mi] = *(const short8*)&As[(wm + mi * 16 + l15) * 32 + qd * 8];
#pragma unroll
    for (int ni = 0; ni < 4; ni++) bf[ni] = *(const short8*)&Bs[(wn + ni * 16 + l15) * 32 + qd * 8];
#pragma unroll
    for (int mi = 0; mi < 4; mi++)
#pragma unroll
      for (int ni = 0; ni < 4; ni++)
        acc[mi][ni] = __builtin_amdgcn_mfma_f32_16x16x32_bf16(af[mi], bf[ni], acc[mi][ni], 0, 0, 0);
  }

#pragma unroll
  for (int ni = 0; ni < 4; ni++) {
    const int c = n0 + wn + ni * 16 + l15;
    const float bv = bias[c];
#pragma unroll
    for (int mi = 0; mi < 4; mi++) {
#pragma unroll
      for (int rg = 0; rg < 4; rg++) {
        const int r = m0 + wm + mi * 16 + qd * 4 + rg;
        float v = acc[mi][ni][rg] + bv;
        if (MODE == 0) {
          ((u16*)outp)[(size_t)r * N + c] = f2b(v);
          if (c >= 1024) {   // v columns: also write masked-v into padded conv input
            const int b = r / T_, t = r - b * T_;
            vmout[((size_t)b * TP_ + t + 5) * D_ + (c - 1024)] = f2b(v * masks[r]);
          }
        } else if (MODE == 1) {
          const size_t idx = (size_t)r * N + c;
          ((float*)outp)[idx] = v + b2f(convb[idx]) + add_f[idx];
        } else if (MODE == 2) {
          ((u16*)outp)[(size_t)r * N + c] = f2b(fmaxf(v, 0.f));
        } else {
          const size_t idx = (size_t)r * N + c;
          ((float*)outp)[idx] = v + add_f[idx];
        }
      }
    }
  }
}

// =====================================================================
// FSMN conv1d as halo-A tap-stationary GEMM.
// Block: 256 m-rows x 64 n-cols, full K=5632. Grid 55*8=440; bx&7 = n-tile
// (one per XCD -> B 720 KB pinned per XCD, A read once per XCD).
// Per 32-wide i-chunk kc: stage 288-row vmpad halo once (covers all 11 taps,
// incl. one batch-boundary jump of +10) + 11 tap B-chunks; then 176 MFMA/wave
// between barriers. Epilogue: convb = (conv + vm) * mask   (bf16, final).
// LDS 62 KB -> 2 blocks/CU.
// =====================================================================
__global__ __launch_bounds__(256, 2)
void conv_gemm(const u16* __restrict__ vmpad, const u16* __restrict__ Wt,
               const float* __restrict__ masks, u16* __restrict__ convb)
{
  __shared__ u16 As[288 * 32];       // 18432 B
  __shared__ u16 Bs[11 * 64 * 32];   // 45056 B

  const int nt = blockIdx.x & 7, mt = blockIdx.x >> 3;
  const int m0 = mt * 256, n0 = nt * 64;
  const int b0 = m0 / T_;
  const int base = m0 + 10 * b0;     // vmpad row of m-row m0

  const int tid = threadIdx.x, lane = tid & 63, w = tid >> 6;
  const int wm = (w >> 1) * 128, wn = (w & 1) * 32;
  const int l15 = lane & 15, qd = lane >> 4;
  const int rl = lane >> 2, ce = (lane & 3) * 8;

  // per-mi A row offsets (halo-adjusted: +10 per batch boundary crossed)
  int arow[8];
#pragma unroll
  for (int mi = 0; mi < 8; mi++) {
    const int mo = wm + mi * 16 + l15;
    const int db = (m0 + mo) / T_ - b0;
    arow[mi] = mo + 10 * db;
  }

  const f32x4 z4 = {0.f, 0.f, 0.f, 0.f};
  f32x4 acc[8][2];
#pragma unroll
  for (int i = 0; i < 8; i++) { acc[i][0] = z4; acc[i][1] = z4; }

  for (int kc = 0; kc < 16; kc++) {
    const int kb = kc * 32;
    __syncthreads();
    // A halo: 18 chunks of 16 rows
    for (int c = w; c < 18; c += 4)
      gll16(vmpad + (size_t)(base + c * 16 + rl) * D_ + kb + ce, As + c * 512);
    // B: 44 chunks = tap*4 + q
    for (int c = w; c < 44; c += 4) {
      const int tap = c >> 2, q = c & 3;
      gll16(Wt + (size_t)(n0 + q * 16 + rl) * KC_ + tap * 512 + kb + ce,
            Bs + c * 512);
    }
    __syncthreads();
#pragma unroll
    for (int tap = 0; tap < 11; tap++) {
      short8 bf0 = *(const short8*)&Bs[tap * 2048 + (wn + l15) * 32 + qd * 8];
      short8 bf1 = *(const short8*)&Bs[tap * 2048 + (wn + 16 + l15) * 32 + qd * 8];
#pragma unroll
      for (int mi = 0; mi < 8; mi++) {
        short8 af = *(const short8*)&As[(arow[mi] + tap) * 32 + qd * 8];
        acc[mi][0] = __builtin_amdgcn_mfma_f32_16x16x32_bf16(af, bf0, acc[mi][0], 0, 0, 0);
        acc[mi][1] = __builtin_amdgcn_mfma_f32_16x16x32_bf16(af, bf1, acc[mi][1], 0, 0, 0);
      }
    }
  }

  // epilogue: convb = (acc + vm) * mask  (bf16, final fsmn output)
#pragma unroll
  for (int mi = 0; mi < 8; mi++) {
#pragma unroll
    for (int rg = 0; rg < 4; rg++) {
      const int r = m0 + wm + mi * 16 + qd * 4 + rg;
      if (r < M_) {
        const int b = r / T_;
        const int vrow = r + 10 * b + 5;      // center-tap vmpad row
        const float m = masks[r];
#pragma unroll
        for (int ni = 0; ni < 2; ni++) {
          const int c = n0 + wn + ni * 16 + l15;
          const float vm = b2f(vmpad[(size_t)vrow * D_ + c]);
          convb[(size_t)r * D_ + c] = f2b((acc[mi][ni][rg] + vm) * m);
        }
      }
    }
  }
}

// =====================================================================
// Fused attention: per (q-tile of 64, bh) block computes
// P = softmax(mask(QK^T/sqrt(dk))) entirely in LDS, then ctx = P@V.
// =====================================================================
__global__ __launch_bounds__(256, 2)
void attn_fused(const u16* __restrict__ qkv, const float* __restrict__ masks,
                u16* __restrict__ ctx)
{
  __shared__ u16 smem[29696];        // 59392 B
  __shared__ float red0[4][64];
  __shared__ float red1[4][64];
  u16* Qs = smem;                    // [64][136] phase 1
  u16* Ks = smem + 64 * 136;         // [64][136]
  u16* Ps = smem;                    // [64][232] phase 2 (aliases Qs)
  u16* Vs = smem + 64 * 232;         // [64][232]

  const int tid = threadIdx.x, lane = tid & 63, w = tid >> 6;
  const int l15 = lane & 15, qd = lane >> 4;
  const int bh = blockIdx.y, b = bh >> 2, h = bh & 3;
  const int q0 = blockIdx.x * 64;
  const uint4 uz = make_uint4(0, 0, 0, 0);

#pragma unroll
  for (int i = 0; i < 4; i++) {
    const int ch = tid + i * 256;
    const int row = ch >> 4, cg = (ch & 15) * 8;
    const int t = q0 + row;
    uint4 v = uz;
    if (t < T_) v = *(const uint4*)(qkv + ((size_t)b * T_ + t) * N3_ + h * DK_ + cg);
    *(uint4*)&Qs[row * 136 + cg] = v;
  }

  const f32x4 z4 = {0.f, 0.f, 0.f, 0.f};
  f32x4 acc[4][4];
#pragma unroll
  for (int i = 0; i < 4; i++)
#pragma unroll
    for (int j = 0; j < 4; j++) acc[i][j] = z4;

#pragma unroll
  for (int kc = 0; kc < 4; kc++) {
    __syncthreads();
#pragma unroll
    for (int i = 0; i < 4; i++) {
      const int ch = tid + i * 256;
      const int row = ch >> 4, cg = (ch & 15) * 8;
      const int t = kc * 64 + row;
      uint4 v = uz;
      if (t < T_) v = *(const uint4*)(qkv + ((size_t)b * T_ + t) * N3_ + D_ + h * DK_ + cg);
      *(uint4*)&Ks[row * 136 + cg] = v;
    }
    __syncthreads();
#pragma unroll
    for (int ks = 0; ks < 4; ks++) {
      short8 bf = *(const short8*)&Ks[(w * 16 + l15) * 136 + ks * 32 + qd * 8];
#pragma unroll
      for (int mi = 0; mi < 4; mi++) {
        short8 af = *(const short8*)&Qs[(mi * 16 + l15) * 136 + ks * 32 + qd * 8];
        acc[kc][mi] = __builtin_amdgcn_mfma_f32_16x16x32_bf16(af, bf, acc[kc][mi], 0, 0, 0);
      }
    }
  }

  const float scale = 0.08838834764831845f;  // 1/sqrt(128)
  const int colb = w * 16 + l15;
  bool valid[4];
#pragma unroll
  for (int kc = 0; kc < 4; kc++) {
    const int col = kc * 64 + colb;
    valid[kc] = (col < T_) && (masks[b * T_ + col] > 0.f);
  }

  float mx[4][4];
#pragma unroll
  for (int mi = 0; mi < 4; mi++)
#pragma unroll
    for (int rg = 0; rg < 4; rg++) {
      float m = -1e30f;
#pragma unroll
      for (int kc = 0; kc < 4; kc++)
        if (valid[kc]) m = fmaxf(m, acc[kc][mi][rg] * scale);
      for (int d = 1; d < 16; d <<= 1) m = fmaxf(m, __shfl_xor(m, d, 64));
      mx[mi][rg] = m;
    }
  if (l15 == 0) {
#pragma unroll
    for (int mi = 0; mi < 4; mi++)
#pragma unroll
      for (int rg = 0; rg < 4; rg++) red0[w][mi * 16 + qd * 4 + rg] = mx[mi][rg];
  }
  __syncthreads();
#pragma unroll
  for (int mi = 0; mi < 4; mi++)
#pragma unroll
    for (int rg = 0; rg < 4; rg++) {
      const int r = mi * 16 + qd * 4 + rg;
      mx[mi][rg] = fmaxf(fmaxf(red0[0][r], red0[1][r]), fmaxf(red0[2][r], red0[3][r]));
    }
  float sm[4][4];
#pragma unroll
  for (int mi = 0; mi < 4; mi++)
#pragma unroll
    for (int rg = 0; rg < 4; rg++) {
      float s = 0.f;
#pragma unroll
      for (int kc = 0; kc < 4; kc++)
        if (valid[kc]) s += __expf(acc[kc][mi][rg] * scale - mx[mi][rg]);
      for (int d = 1; d < 16; d <<= 1) s += __shfl_xor(s, d, 64);
      sm[mi][rg] = s;
    }
  if (l15 == 0) {
#pragma unroll
    for (int mi = 0; mi < 4; mi++)
#pragma unroll
      for (int rg = 0; rg < 4; rg++) red1[w][mi * 16 + qd * 4 + rg] = sm[mi][rg];
  }
  __syncthreads();
#pragma unroll
  for (int mi = 0; mi < 4; mi++)
#pragma unroll
    for (int rg = 0; rg < 4; rg++) {
      const int r = mi * 16 + qd * 4 + rg;
      const float inv = 1.f / (red1[0][r] + red1[1][r] + red1[2][r] + red1[3][r]);
#pragma unroll
      for (int kc = 0; kc < 4; kc++) {
        const int col = kc * 64 + colb;
        if (col < 224) {
          const float p = valid[kc] ? __expf(acc[kc][mi][rg] * scale - mx[mi][rg]) * inv : 0.f;
          Ps[r * 232 + col] = f2b(p);
        }
      }
    }

  // ---- phase 2: ctx = P @ V, per 64-d half ----
  const int kvg = tid >> 4, dg = tid & 15;
#pragma unroll
  for (int half = 0; half < 2; ++half) {
    __syncthreads();
#pragma unroll
    for (int r = 0; r < 14; ++r) {
      const int kv = r * 16 + kvg;
      ushort4 vv = make_ushort4(0, 0, 0, 0);
      if (kv < T_)
        vv = *(const ushort4*)(qkv + ((size_t)b * T_ + kv) * N3_ + 1024 + h * DK_ + half * 64 + dg * 4);
      Vs[(dg * 4 + 0) * 232 + kv] = vv.x;
      Vs[(dg * 4 + 1) * 232 + kv] = vv.y;
      Vs[(dg * 4 + 2) * 232 + kv] = vv.z;
      Vs[(dg * 4 + 3) * 232 + kv] = vv.w;
    }
    __syncthreads();
    f32x4 a2[4] = {z4, z4, z4, z4};
#pragma unroll
    for (int k0 = 0; k0 < 7; ++k0) {
      short8 af = *(const short8*)&Ps[(w * 16 + l15) * 232 + k0 * 32 + qd * 8];
#pragma unroll
      for (int nt = 0; nt < 4; ++nt) {
        short8 bf = *(const short8*)&Vs[(nt * 16 + l15) * 232 + k0 * 32 + qd * 8];
        a2[nt] = __builtin_amdgcn_mfma_f32_16x16x32_bf16(af, bf, a2[nt], 0, 0, 0);
      }
    }
    const int tb = q0 + w * 16 + qd * 4;
#pragma unroll
    for (int nt = 0; nt < 4; ++nt) {
      const int d = h * DK_ + half * 64 + nt * 16 + l15;
#pragma unroll
      for (int rg = 0; rg < 4; ++rg) {
        const int tt = tb + rg;
        if (tt < T_) ctx[((size_t)b * T_ + tt) * D_ + d] = f2b(a2[nt][rg]);
      }
    }
  }
}

// ======================= small support kernels =======================
__global__ __launch_bounds__(256)
void ln_k(const float* __restrict__ x, const float* __restrict__ wgt,
          const float* __restrict__ bia, u16* __restrict__ outp)
{
  const int lane = threadIdx.x & 63, wv = threadIdx.x >> 6;
  const size_t row = (size_t)blockIdx.x * 4 + wv;
  const float* rp = x + row * D_ + lane * 8;
  float v[8], s = 0.f, s2 = 0.f;
  float4 r0 = *(const float4*)rp;
  float4 r1 = *(const float4*)(rp + 4);
  v[0] = r0.x; v[1] = r0.y; v[2] = r0.z; v[3] = r0.w;
  v[4] = r1.x; v[5] = r1.y; v[6] = r1.z; v[7] = r1.w;
#pragma unroll
  for (int i = 0; i < 8; i++) { s += v[i]; s2 += v[i] * v[i]; }
  for (int d = 1; d < 64; d <<= 1) { s += __shfl_xor(s, d, 64); s2 += __shfl_xor(s2, d, 64); }
  const float mean = s * (1.f / 512.f);
  const float var  = s2 * (1.f / 512.f) - mean * mean;
  const float rs   = rsqrtf(var + 1e-5f);
  float4 w0 = *(const float4*)(wgt + lane * 8);
  float4 w1 = *(const float4*)(wgt + lane * 8 + 4);
  float4 b0 = *(const float4*)(bia + lane * 8);
  float4 b1 = *(const float4*)(bia + lane * 8 + 4);
  const float wv8[8] = {w0.x, w0.y, w0.z, w0.w, w1.x, w1.y, w1.z, w1.w};
  const float bv8[8] = {b0.x, b0.y, b0.z, b0.w, b1.x, b1.y, b1.z, b1.w};
  U8 o;
#pragma unroll
  for (int i = 0; i < 8; i++)
    o.u[i] = f2b((v[i] - mean) * rs * wv8[i] + bv8[i]);
  *(uint4*)(outp + row * D_ + lane * 8) = o.v;
}

// =====================================================================
// Merged prep: 4 weight transposes (fp32 KxN -> bf16 NxK), fsmn reorder
// (o,i,tap)->(o, tap*512+i), vmpad pad-row zeroing (incl. overrun slack).
// =====================================================================
__global__ __launch_bounds__(256)
void prep_all(const float* __restrict__ qkv_w, const float* __restrict__ out_w,
              const float* __restrict__ w1, const float* __restrict__ w2,
              const float* __restrict__ fsmn_w,
              u16* __restrict__ qkv_wT, u16* __restrict__ out_wT,
              u16* __restrict__ w1T, u16* __restrict__ w2T,
              u16* __restrict__ fsmnW2, u16* __restrict__ vmpad)
{
  const int bid = blockIdx.x;
  if (bid < 3072) {
    const float* src; u16* dst; int K, N, tb;
    if (bid < 768)       { src = qkv_w; dst = qkv_wT; K = 512;  N = 1536; tb = bid; }
    else if (bid < 1024) { src = out_w; dst = out_wT; K = 512;  N = 512;  tb = bid - 768; }
    else if (bid < 2048) { src = w1;    dst = w1T;    K = 512;  N = 2048; tb = bid - 1024; }
    else                 { src = w2;    dst = w2T;    K = 2048; N = 512;  tb = bid - 2048; }
    const int ktiles = K / 32;
    const int k0 = (tb % ktiles) * 32, n0 = (tb / ktiles) * 32;
    __shared__ float tile[32][33];
    const int x = threadIdx.x & 31, y = threadIdx.x >> 5;
#pragma unroll
    for (int j = 0; j < 4; j++)
      tile[y + j * 8][x] = src[(size_t)(k0 + y + j * 8) * N + n0 + x];
    __syncthreads();
#pragma unroll
    for (int j = 0; j < 4; j++)
      dst[(size_t)(n0 + y + j * 8) * K + k0 + x] = f2b(tile[x][y + j * 8]);
  } else if (bid < 4096) {
    const int idx = (bid - 3072) * 256 + threadIdx.x;   // o*512+i
    const int o = idx >> 9, i = idx & 511;
    const float* s = fsmn_w + (size_t)idx * 11;
#pragma unroll
    for (int tap = 0; tap < 11; ++tap)
      fsmnW2[(size_t)o * KC_ + tap * 512 + i] = f2b(s[tap]);
  } else {
    // zero pad rows: per-batch rows 0..4 and 223..227, plus 320-row tail slack
    const int e8 = (bid - 4096) * 256 + threadIdx.x;  // uint4 index
    const int e  = e8 * 8;
    const int c  = e & 511;
    const int pr = e >> 9;              // padded-row ordinal
    int row;
    if (pr < 640) {                     // 10 pad rows per batch
      const int b = pr / 10, j = pr % 10;
      row = b * TP_ + ((j < 5) ? j : (218 + j));
    } else {                            // tail slack rows (halo overrun)
      row = B_ * TP_ + (pr - 640);      // rows 14592..14911
    }
    *(uint4*)(vmpad + (size_t)row * D_ + c) = make_uint4(0, 0, 0, 0);
  }
}

// =====================================================================
extern "C" void kernel_launch(void* const* d_in, const int* in_sizes, int n_in,
                              void* d_out, int out_size, void* d_ws, size_t ws_size,
                              hipStream_t stream)
{
  const float* x      = (const float*)d_in[0];
  const float* masks  = (const float*)d_in[1];
  const float* ln0_w  = (const float*)d_in[2];
  const float* ln0_b  = (const float*)d_in[3];
  const float* ln1_w  = (const float*)d_in[4];
  const float* ln1_b  = (const float*)d_in[5];
  const float* qkv_w  = (const float*)d_in[6];
  const float* qkv_b  = (const float*)d_in[7];
  const float* out_w  = (const float*)d_in[8];
  const float* out_b  = (const float*)d_in[9];
  const float* fsmn_w = (const float*)d_in[10];
  const float* w1     = (const float*)d_in[11];
  const float* b1     = (const float*)d_in[12];
  const float* w2     = (const float*)d_in[13];
  const float* b2     = (const float*)d_in[14];
  float* outp = (float*)d_out;
  u16* ws   = (u16*)d_ws;

  size_t off = 0;
  u16* qkv_wT = ws + off; off += (size_t)1536 * 512;
  u16* out_wT = ws + off; off += (size_t)512 * 512;
  u16* w1T    = ws + off; off += (size_t)2048 * 512;
  u16* w2T    = ws + off; off += (size_t)512 * 2048;
  u16* fsmnW2 = ws + off; off += (size_t)512 * KC_;       // (512o, 5632k)
  u16* slotA  = ws + off; off += (size_t)M_ * 512;        // h (ln0) -> ctx
  u16* qkvb   = ws + off; off += (size_t)M_ * 1536;       // qkv; later h1 + x1
  u16* vmpad  = ws + off; off += (size_t)(B_ * TP_ + 320) * 512;  // + halo slack
  u16* regionX= ws + off;
  // regionX: convb (M*512 bf16) dead after out-proj; hid (M*2048 bf16) live
  // from ffn1 -> alias.
  u16* convb  = regionX;                                   // M*512 bf16
  u16* hid    = regionX;                                   // M*2048 bf16
  u16* h1     = qkvb;                                      // M*512 bf16
  float* x1   = (float*)(qkvb + (size_t)M_ * 512);         // M*512 fp32

  // weight prep + vmpad pad-row/slack zeroing, one launch (4096 + 30 blocks)
  prep_all<<<4126, 256, 0, stream>>>(qkv_w, out_w, w1, w2, fsmn_w,
                                     qkv_wT, out_wT, w1T, w2T, fsmnW2, vmpad);
  // ln0 -> h
  ln_k<<<M_ / 4, 256, 0, stream>>>(x, ln0_w, ln0_b, slotA);
  // qkv = h @ qkv_w + b  (bf16 out; v-cols also populate vmpad interior)
  gemm_u<0><<<8 * 14 * 12, 256, 0, stream>>>(
      slotA, 512, qkv_wT, 512, qkv_b, nullptr, vmpad, nullptr, qkvb,
      1536, 512, 12, masks);
  // fsmn conv: halo-A tap-stationary GEMM -> convb = (conv+vm)*mask
  conv_gemm<<<55 * 8, 256, 0, stream>>>(vmpad, fsmnW2, masks, convb);
  // fused attention -> ctx in slotA
  attn_fused<<<dim3(4, 256), 256, 0, stream>>>(qkvb, masks, slotA);
  // x1 = x + ctx@out_w + out_b + convb   (fp32 out)
  gemm_u<1><<<8 * 14 * 4, 256, 0, stream>>>(
      slotA, 512, out_wT, 512, out_b, convb, nullptr, x, x1,
      512, 512, 4, masks);
  // ffn
  ln_k<<<M_ / 4, 256, 0, stream>>>(x1, ln1_w, ln1_b, h1);
  gemm_u<2><<<8 * 14 * 16, 256, 0, stream>>>(
      h1, 512, w1T, 512, b1, nullptr, nullptr, nullptr, hid,
      2048, 512, 16, nullptr);
  gemm_u<3><<<8 * 14 * 4, 256, 0, stream>>>(
      hid, 2048, w2T, 2048, b2, nullptr, nullptr, x1, outp,
      512, 2048, 4, nullptr);
}